// Round 1
// baseline (2536.121 us; speedup 1.0000x reference)
//
#include <hip/hip_runtime.h>
#include <hip/hip_bf16.h>

#define NPIX 65536
#define IW 256
#define NCHK 64   // gram n-chunks (each 1024 px = 4 image rows)

// ---------------- K1: qkv_pre[m][n] = sum_k w_qkv[m*192+k] * x[k*NPIX+n]
// M=576, K=192, N=65536. BM=64 BN=256 BK=8, 256 threads, 8x8 micro-tile.
__global__ __launch_bounds__(256) void k1_qkv_gemm(const float* __restrict__ w,
                                                   const float* __restrict__ x,
                                                   float* __restrict__ out) {
    __shared__ float As[8][64];
    __shared__ float Bs[8][256];
    const int tid = threadIdx.x;
    const int m_base = blockIdx.y * 64;
    const long n_base = (long)blockIdx.x * 256;
    const int tm = tid & 7;    // m group 0..7
    const int tn = tid >> 3;   // n group 0..31
    float acc[8][8];
    #pragma unroll
    for (int i = 0; i < 8; i++)
        #pragma unroll
        for (int j = 0; j < 8; j++) acc[i][j] = 0.f;

    for (int kc = 0; kc < 192; kc += 8) {
        __syncthreads();
        if (tid < 128) {  // stage A (64m x 8k), transposed into As[k][m]
            int mm = tid >> 1;
            int kq = (tid & 1) * 4;
            float4 v = *reinterpret_cast<const float4*>(w + (m_base + mm) * 192 + kc + kq);
            As[kq + 0][mm] = v.x; As[kq + 1][mm] = v.y;
            As[kq + 2][mm] = v.z; As[kq + 3][mm] = v.w;
        }
        #pragma unroll
        for (int e = 0; e < 2; e++) {  // stage B (8k x 256n) as float4
            int f4 = tid + 256 * e;
            int kk = f4 >> 6;
            int nn4 = f4 & 63;
            float4 v = *reinterpret_cast<const float4*>(x + (long)(kc + kk) * NPIX + n_base + nn4 * 4);
            *reinterpret_cast<float4*>(&Bs[kk][nn4 * 4]) = v;
        }
        __syncthreads();
        #pragma unroll
        for (int k = 0; k < 8; k++) {
            float a[8], bb[8];
            *reinterpret_cast<float4*>(&a[0]) = *reinterpret_cast<const float4*>(&As[k][tm * 8]);
            *reinterpret_cast<float4*>(&a[4]) = *reinterpret_cast<const float4*>(&As[k][tm * 8 + 4]);
            *reinterpret_cast<float4*>(&bb[0]) = *reinterpret_cast<const float4*>(&Bs[k][tn * 8]);
            *reinterpret_cast<float4*>(&bb[4]) = *reinterpret_cast<const float4*>(&Bs[k][tn * 8 + 4]);
            #pragma unroll
            for (int i = 0; i < 8; i++)
                #pragma unroll
                for (int j = 0; j < 8; j++) acc[i][j] += a[i] * bb[j];
        }
    }
    #pragma unroll
    for (int i = 0; i < 8; i++) {
        long row = m_base + tm * 8 + i;
        float* dst = out + row * NPIX + n_base + tn * 8;
        float4 v0 = {acc[i][0], acc[i][1], acc[i][2], acc[i][3]};
        float4 v1 = {acc[i][4], acc[i][5], acc[i][6], acc[i][7]};
        *reinterpret_cast<float4*>(dst) = v0;
        *reinterpret_cast<float4*>(dst + 4) = v1;
    }
}

// ---------------- K2: fused depthwise-3x3 + Gram S=Q~K~^T + sumsq(q),sumsq(k)
// grid (NCHK chunks, 4 heads); q,k never hit HBM.
__global__ __launch_bounds__(256) void k2_gram(const float* __restrict__ qkv,
                                               const float* __restrict__ wdw,
                                               float* __restrict__ Sp,   // [4][NCHK][48][48]
                                               float* __restrict__ sqq,  // [192][NCHK]
                                               float* __restrict__ sqk) {
    __shared__ float qs[48][132];
    __shared__ float ks[48][132];
    __shared__ float wl[96][9];
    const int tid = threadIdx.x;
    const int chunk = blockIdx.x;
    const int h = blockIdx.y;
    for (int e = tid; e < 96 * 9; e += 256) {
        int cl = e / 9, t = e % 9;
        int chg = (cl < 48) ? (h * 48 + cl) : (192 + h * 48 + (cl - 48));
        wl[cl][t] = wdw[chg * 9 + t];
    }
    float g[9];
    #pragma unroll
    for (int i = 0; i < 9; i++) g[i] = 0.f;
    float ss = 0.f;
    const int c0 = 3 * (tid >> 4);
    const int d0 = 3 * (tid & 15);
    const int y0 = chunk * 4;

    for (int sub = 0; sub < 8; sub++) {
        int y = y0 + (sub >> 1);
        int x0 = (sub & 1) * 128;
        __syncthreads();
        for (int idx = tid; idx < 96 * 128; idx += 256) {
            int cl = idx >> 7, p = idx & 127;
            int x = x0 + p;
            int chg = (cl < 48) ? (h * 48 + cl) : (192 + h * 48 + (cl - 48));
            const float* src = qkv + (long)chg * NPIX;
            float a = 0.f;
            #pragma unroll
            for (int dy = -1; dy <= 1; dy++) {
                int yy = y + dy;
                if (yy < 0 || yy > 255) continue;
                #pragma unroll
                for (int dx = -1; dx <= 1; dx++) {
                    int xx = x + dx;
                    if (xx < 0 || xx > 255) continue;
                    a += wl[cl][(dy + 1) * 3 + (dx + 1)] * src[yy * IW + xx];
                }
            }
            if (cl < 48) qs[cl][p] = a; else ks[cl - 48][p] = a;
        }
        __syncthreads();
        #pragma unroll 4
        for (int p4 = 0; p4 < 32; p4++) {
            float4 qa[3], ka[3];
            #pragma unroll
            for (int i = 0; i < 3; i++) qa[i] = *reinterpret_cast<const float4*>(&qs[c0 + i][p4 * 4]);
            #pragma unroll
            for (int j = 0; j < 3; j++) ka[j] = *reinterpret_cast<const float4*>(&ks[d0 + j][p4 * 4]);
            #pragma unroll
            for (int i = 0; i < 3; i++)
                #pragma unroll
                for (int j = 0; j < 3; j++)
                    g[i * 3 + j] += qa[i].x * ka[j].x + qa[i].y * ka[j].y +
                                    qa[i].z * ka[j].z + qa[i].w * ka[j].w;
        }
        if (tid < 96) {
            const float* row = (tid < 48) ? &qs[tid][0] : &ks[tid - 48][0];
            for (int p4 = 0; p4 < 32; p4++) {
                float4 v = *reinterpret_cast<const float4*>(row + p4 * 4);
                ss += v.x * v.x + v.y * v.y + v.z * v.z + v.w * v.w;
            }
        }
    }
    long base = ((long)h * NCHK + chunk) * 2304;
    #pragma unroll
    for (int i = 0; i < 3; i++)
        #pragma unroll
        for (int j = 0; j < 3; j++)
            Sp[base + (c0 + i) * 48 + (d0 + j)] = g[i * 3 + j];
    if (tid < 48) sqq[(h * 48 + tid) * NCHK + chunk] = ss;
    else if (tid < 96) sqk[(h * 48 + (tid - 48)) * NCHK + chunk] = ss;
}

// ---------------- K3: reduce partials, norms, noise MLP, softmax -> attn[4][48][48]
__global__ __launch_bounds__(256) void k3_attn(const float* __restrict__ Sp,
                                               const float* __restrict__ sqq,
                                               const float* __restrict__ sqk,
                                               const float* __restrict__ noise,
                                               const float* __restrict__ btemp,
                                               const float* __restrict__ w_nm1,
                                               const float* __restrict__ w_nm2,
                                               float* __restrict__ attn, int b) {
    __shared__ float sA[48][49];
    __shared__ float invq[48], invk[48];
    __shared__ float stemp;
    const int h = blockIdx.x, tid = threadIdx.x;
    for (int e = tid; e < 2304; e += 256) {
        float s = 0.f;
        const float* p = Sp + (long)h * NCHK * 2304 + e;
        for (int ch = 0; ch < NCHK; ch++) s += p[ch * 2304];
        sA[e / 48][e % 48] = s;
    }
    if (tid < 96) {
        const float* p = (tid < 48) ? (sqq + (h * 48 + tid) * NCHK)
                                    : (sqk + (h * 48 + (tid - 48)) * NCHK);
        float s = 0.f;
        for (int ch = 0; ch < NCHK; ch++) s += p[ch];
        float inv = 1.f / fmaxf(sqrtf(s), 1e-12f);
        if (tid < 48) invq[tid] = inv; else invk[tid - 48] = inv;
    }
    if (tid == 0) {
        float nz = noise[b];
        float a = 0.f;
        for (int i = 0; i < 48; i++) {
            float t = w_nm1[i] * nz;
            t = (t >= 0.f) ? t : 0.2f * t;
            a += w_nm2[h * 48 + i] * t;
        }
        float sig = 1.f / (1.f + expf(-a));
        stemp = btemp[h] * (2.f - sig);
    }
    __syncthreads();
    for (int e = tid; e < 2304; e += 256) {
        int c = e / 48, d = e % 48;
        sA[c][d] *= invq[c] * invk[d] * stemp;
    }
    __syncthreads();
    if (tid < 48) {
        float m = -1e30f;
        for (int d = 0; d < 48; d++) m = fmaxf(m, sA[tid][d]);
        float sum = 0.f;
        for (int d = 0; d < 48; d++) {
            float e_ = expf(sA[tid][d] - m);
            sA[tid][d] = e_;
            sum += e_;
        }
        float r = 1.f / sum;
        for (int d = 0; d < 48; d++)
            attn[h * 2304 + tid * 48 + d] = sA[tid][d] * r;
    }
}

// ---------------- K4: W_eff[o][j] = sum_c w_out[o][h*48+c] * attn[h][c][d]  (j=h*48+d)
__global__ __launch_bounds__(256) void k4_weff(const float* __restrict__ w_out,
                                               const float* __restrict__ attn,
                                               float* __restrict__ weff) {
    int e = blockIdx.x * 256 + threadIdx.x;  // < 36864
    int o = e / 192, j = e % 192;
    int h = j / 48, d = j % 48;
    const float* wr = w_out + o * 192 + h * 48;
    const float* ar = attn + h * 2304 + d;
    float s = 0.f;
    #pragma unroll
    for (int c = 0; c < 48; c++) s += wr[c] * ar[c * 48];
    weff[e] = s;
}

// ---------------- K5: out[o][n] = sum_j weff[o][j] * dw(qkv_pre[384+j])[n]
// grid (512 n-tiles of 128, 2 o-tiles of 96). v never materialized.
__global__ __launch_bounds__(256) void k5_out_gemm(const float* __restrict__ weff,
                                                   const float* __restrict__ qkv,
                                                   const float* __restrict__ wdw,
                                                   float* __restrict__ out) {
    __shared__ float Vs[8][128];
    __shared__ float Ws[8][96];
    __shared__ float wv[192 * 9];
    const int tid = threadIdx.x;
    const int nb = blockIdx.x;
    const int o_base = blockIdx.y * 96;
    const long n_base = (long)nb * 128;
    const int y = nb >> 1;
    const int x0 = (nb & 1) * 128;
    for (int e = tid; e < 1728; e += 256) wv[e] = wdw[384 * 9 + e];
    const int og = tid >> 5;   // 0..7 -> 12 contiguous o each
    const int ng = tid & 31;   // n = ng + 32*ii
    float acc[12][4];
    #pragma unroll
    for (int r = 0; r < 12; r++)
        #pragma unroll
        for (int ii = 0; ii < 4; ii++) acc[r][ii] = 0.f;

    for (int j0 = 0; j0 < 192; j0 += 8) {
        __syncthreads();
        for (int e = tid; e < 768; e += 256) {  // Ws[jj][oo]
            int oo = e >> 3, jj = e & 7;
            Ws[jj][oo] = weff[(o_base + oo) * 192 + j0 + jj];
        }
        for (int e = tid; e < 1024; e += 256) {  // Vs with fused dw
            int jj = e >> 7, p = e & 127;
            int j = j0 + jj;
            int x = x0 + p;
            const float* src = qkv + (long)(384 + j) * NPIX;
            const float* wp = &wv[j * 9];
            float a = 0.f;
            #pragma unroll
            for (int dy = -1; dy <= 1; dy++) {
                int yy = y + dy;
                if (yy < 0 || yy > 255) continue;
                #pragma unroll
                for (int dx = -1; dx <= 1; dx++) {
                    int xx = x + dx;
                    if (xx < 0 || xx > 255) continue;
                    a += wp[(dy + 1) * 3 + (dx + 1)] * src[yy * IW + xx];
                }
            }
            Vs[jj][p] = a;
        }
        __syncthreads();
        #pragma unroll
        for (int jj = 0; jj < 8; jj++) {
            float wr[12];
            *reinterpret_cast<float4*>(&wr[0]) = *reinterpret_cast<const float4*>(&Ws[jj][og * 12]);
            *reinterpret_cast<float4*>(&wr[4]) = *reinterpret_cast<const float4*>(&Ws[jj][og * 12 + 4]);
            *reinterpret_cast<float4*>(&wr[8]) = *reinterpret_cast<const float4*>(&Ws[jj][og * 12 + 8]);
            float vv[4];
            #pragma unroll
            for (int ii = 0; ii < 4; ii++) vv[ii] = Vs[jj][ng + 32 * ii];
            #pragma unroll
            for (int r = 0; r < 12; r++)
                #pragma unroll
                for (int ii = 0; ii < 4; ii++) acc[r][ii] += wr[r] * vv[ii];
        }
    }
    #pragma unroll
    for (int r = 0; r < 12; r++) {
        long row = o_base + og * 12 + r;
        #pragma unroll
        for (int ii = 0; ii < 4; ii++)
            out[row * NPIX + n_base + ng + 32 * ii] = acc[r][ii];
    }
}

extern "C" void kernel_launch(void* const* d_in, const int* in_sizes, int n_in,
                              void* d_out, int out_size, void* d_ws, size_t ws_size,
                              hipStream_t stream) {
    const float* x      = (const float*)d_in[0];
    const float* noise  = (const float*)d_in[1];
    const float* btemp  = (const float*)d_in[2];
    const float* w_nm1  = (const float*)d_in[3];
    const float* w_nm2  = (const float*)d_in[4];
    const float* w_qkv  = (const float*)d_in[5];
    const float* w_dw   = (const float*)d_in[6];
    const float* w_out  = (const float*)d_in[7];
    float* out = (float*)d_out;
    float* ws = (float*)d_ws;

    float* qkv_pre = ws;                        // 576*65536 = 37748736 floats
    float* Sp   = qkv_pre + 37748736;           // 4*64*2304 = 589824
    float* sqq  = Sp + 589824;                  // 192*64 = 12288
    float* sqk  = sqq + 12288;                  // 12288
    float* attn = sqk + 12288;                  // 9216
    float* weff = attn + 9216;                  // 36864

    for (int b = 0; b < 2; b++) {
        const float* xb = x + (long)b * 192 * NPIX;
        float* outb = out + (long)b * 192 * NPIX;
        k1_qkv_gemm<<<dim3(256, 9), 256, 0, stream>>>(w_qkv, xb, qkv_pre);
        k2_gram<<<dim3(NCHK, 4), 256, 0, stream>>>(qkv_pre, w_dw, Sp, sqq, sqk);
        k3_attn<<<4, 256, 0, stream>>>(Sp, sqq, sqk, noise, btemp, w_nm1, w_nm2, attn, b);
        k4_weff<<<144, 256, 0, stream>>>(w_out, attn, weff);
        k5_out_gemm<<<dim3(512, 2), 256, 0, stream>>>(weff, qkv_pre, w_dw, outb);
    }
}

// Round 2
// 2114.340 us; speedup vs baseline: 1.1995x; 1.1995x over previous
//
#include <hip/hip_runtime.h>
#include <hip/hip_bf16.h>

#define NPIX 65536
#define IW 256

// ---------------- K1: qkv_pre[m][n] = sum_k w_qkv[m*192+k] * x[k*NPIX+n]
// M=576, K=192, N=65536. BM=64 BN=256 BK=8, 256 threads, 8x8 micro-tile.
__global__ __launch_bounds__(256) void k1_qkv_gemm(const float* __restrict__ w,
                                                   const float* __restrict__ x,
                                                   float* __restrict__ out) {
    __shared__ float As[8][64];
    __shared__ float Bs[8][256];
    const int tid = threadIdx.x;
    const int m_base = blockIdx.y * 64;
    const long n_base = (long)blockIdx.x * 256;
    const int tm = tid & 7;    // m group 0..7
    const int tn = tid >> 3;   // n group 0..31
    float acc[8][8];
    #pragma unroll
    for (int i = 0; i < 8; i++)
        #pragma unroll
        for (int j = 0; j < 8; j++) acc[i][j] = 0.f;

    for (int kc = 0; kc < 192; kc += 8) {
        __syncthreads();
        if (tid < 128) {  // stage A (64m x 8k), transposed into As[k][m]
            int mm = tid >> 1;
            int kq = (tid & 1) * 4;
            float4 v = *reinterpret_cast<const float4*>(w + (m_base + mm) * 192 + kc + kq);
            As[kq + 0][mm] = v.x; As[kq + 1][mm] = v.y;
            As[kq + 2][mm] = v.z; As[kq + 3][mm] = v.w;
        }
        #pragma unroll
        for (int e = 0; e < 2; e++) {  // stage B (8k x 256n) as float4
            int f4 = tid + 256 * e;
            int kk = f4 >> 6;
            int nn4 = f4 & 63;
            float4 v = *reinterpret_cast<const float4*>(x + (long)(kc + kk) * NPIX + n_base + nn4 * 4);
            *reinterpret_cast<float4*>(&Bs[kk][nn4 * 4]) = v;
        }
        __syncthreads();
        #pragma unroll
        for (int k = 0; k < 8; k++) {
            float a[8], bb[8];
            *reinterpret_cast<float4*>(&a[0]) = *reinterpret_cast<const float4*>(&As[k][tm * 8]);
            *reinterpret_cast<float4*>(&a[4]) = *reinterpret_cast<const float4*>(&As[k][tm * 8 + 4]);
            *reinterpret_cast<float4*>(&bb[0]) = *reinterpret_cast<const float4*>(&Bs[k][tn * 8]);
            *reinterpret_cast<float4*>(&bb[4]) = *reinterpret_cast<const float4*>(&Bs[k][tn * 8 + 4]);
            #pragma unroll
            for (int i = 0; i < 8; i++)
                #pragma unroll
                for (int j = 0; j < 8; j++) acc[i][j] += a[i] * bb[j];
        }
    }
    #pragma unroll
    for (int i = 0; i < 8; i++) {
        long row = m_base + tm * 8 + i;
        float* dst = out + row * NPIX + n_base + tn * 8;
        float4 v0 = {acc[i][0], acc[i][1], acc[i][2], acc[i][3]};
        float4 v1 = {acc[i][4], acc[i][5], acc[i][6], acc[i][7]};
        *reinterpret_cast<float4*>(dst) = v0;
        *reinterpret_cast<float4*>(dst + 4) = v1;
    }
}

// ---------------- K2: fused depthwise-3x3 + Gram partials + sumsq partials
// grid (nchk chunks, 4 heads); each chunk = rpc image rows; q,k never hit HBM.
__global__ __launch_bounds__(256) void k2_gram(const float* __restrict__ qkv,
                                               const float* __restrict__ wdw,
                                               float* __restrict__ Sp,   // [4][nchk][48][48]
                                               float* __restrict__ sqq,  // [192][nchk]
                                               float* __restrict__ sqk,
                                               int nchk, int rpc) {
    __shared__ float qs[48][132];
    __shared__ float ks[48][132];
    __shared__ float wl[96][9];
    const int tid = threadIdx.x;
    const int chunk = blockIdx.x;
    const int h = blockIdx.y;
    for (int e = tid; e < 96 * 9; e += 256) {
        int cl = e / 9, t = e % 9;
        int chg = (cl < 48) ? (h * 48 + cl) : (192 + h * 48 + (cl - 48));
        wl[cl][t] = wdw[chg * 9 + t];
    }
    float g[9];
    #pragma unroll
    for (int i = 0; i < 9; i++) g[i] = 0.f;
    float ss = 0.f;
    const int c0 = 3 * (tid >> 4);
    const int d0 = 3 * (tid & 15);
    const int y0 = chunk * rpc;
    const int nsub = rpc * 2;

    for (int sub = 0; sub < nsub; sub++) {
        int y = y0 + (sub >> 1);
        int x0 = (sub & 1) * 128;
        __syncthreads();
        for (int idx = tid; idx < 96 * 128; idx += 256) {
            int cl = idx >> 7, p = idx & 127;
            int x = x0 + p;
            int chg = (cl < 48) ? (h * 48 + cl) : (192 + h * 48 + (cl - 48));
            const float* src = qkv + (long)chg * NPIX;
            float a = 0.f;
            #pragma unroll
            for (int dy = -1; dy <= 1; dy++) {
                int yy = y + dy;
                if (yy < 0 || yy > 255) continue;
                #pragma unroll
                for (int dx = -1; dx <= 1; dx++) {
                    int xx = x + dx;
                    if (xx < 0 || xx > 255) continue;
                    a += wl[cl][(dy + 1) * 3 + (dx + 1)] * src[yy * IW + xx];
                }
            }
            if (cl < 48) qs[cl][p] = a; else ks[cl - 48][p] = a;
        }
        __syncthreads();
        #pragma unroll 4
        for (int p4 = 0; p4 < 32; p4++) {
            float4 qa[3], ka[3];
            #pragma unroll
            for (int i = 0; i < 3; i++) qa[i] = *reinterpret_cast<const float4*>(&qs[c0 + i][p4 * 4]);
            #pragma unroll
            for (int j = 0; j < 3; j++) ka[j] = *reinterpret_cast<const float4*>(&ks[d0 + j][p4 * 4]);
            #pragma unroll
            for (int i = 0; i < 3; i++)
                #pragma unroll
                for (int j = 0; j < 3; j++)
                    g[i * 3 + j] += qa[i].x * ka[j].x + qa[i].y * ka[j].y +
                                    qa[i].z * ka[j].z + qa[i].w * ka[j].w;
        }
        if (tid < 96) {
            const float* row = (tid < 48) ? &qs[tid][0] : &ks[tid - 48][0];
            for (int p4 = 0; p4 < 32; p4++) {
                float4 v = *reinterpret_cast<const float4*>(row + p4 * 4);
                ss += v.x * v.x + v.y * v.y + v.z * v.z + v.w * v.w;
            }
        }
    }
    long base = ((long)h * nchk + chunk) * 2304;
    #pragma unroll
    for (int i = 0; i < 3; i++)
        #pragma unroll
        for (int j = 0; j < 3; j++)
            Sp[base + (c0 + i) * 48 + (d0 + j)] = g[i * 3 + j];
    if (tid < 48) sqq[(h * 48 + tid) * nchk + chunk] = ss;
    else if (tid < 96) sqk[(h * 48 + (tid - 48)) * nchk + chunk] = ss;
}

// ---------------- K3a: parallel reduce of Gram + sumsq partials
__global__ __launch_bounds__(256) void k3a_reduce(const float* __restrict__ Sp,
                                                  const float* __restrict__ sqq,
                                                  const float* __restrict__ sqk,
                                                  float* __restrict__ S,      // [4][2304]
                                                  float* __restrict__ sumsq,  // [384]
                                                  int nchk) {
    int e = blockIdx.x * 256 + threadIdx.x;
    if (e < 9216) {
        int h = e / 2304, idx = e % 2304;
        const float* p = Sp + (long)h * nchk * 2304 + idx;
        float s = 0.f;
        for (int ch = 0; ch < nchk; ch++) s += p[(long)ch * 2304];
        S[e] = s;
    } else if (e < 9600) {
        int c = e - 9216;  // 0..383: q channels then k channels
        const float* p = (c < 192) ? (sqq + (long)c * nchk) : (sqk + (long)(c - 192) * nchk);
        float s = 0.f;
        for (int ch = 0; ch < nchk; ch++) s += p[ch];
        sumsq[c] = s;
    }
}

// ---------------- K3b: norms, noise MLP, softmax -> attn[4][48][48]
__global__ __launch_bounds__(256) void k3b_attn(const float* __restrict__ S,
                                                const float* __restrict__ sumsq,
                                                const float* __restrict__ noise,
                                                const float* __restrict__ btemp,
                                                const float* __restrict__ w_nm1,
                                                const float* __restrict__ w_nm2,
                                                float* __restrict__ attn, int b) {
    __shared__ float sA[48][49];
    __shared__ float invq[48], invk[48];
    __shared__ float stemp;
    const int h = blockIdx.x, tid = threadIdx.x;
    for (int e = tid; e < 2304; e += 256)
        sA[e / 48][e % 48] = S[h * 2304 + e];
    if (tid < 96) {
        float s = (tid < 48) ? sumsq[h * 48 + tid] : sumsq[192 + h * 48 + (tid - 48)];
        float inv = 1.f / fmaxf(sqrtf(s), 1e-12f);
        if (tid < 48) invq[tid] = inv; else invk[tid - 48] = inv;
    }
    if (tid == 0) {
        float nz = noise[b];
        float a = 0.f;
        for (int i = 0; i < 48; i++) {
            float t = w_nm1[i] * nz;
            t = (t >= 0.f) ? t : 0.2f * t;
            a += w_nm2[h * 48 + i] * t;
        }
        float sig = 1.f / (1.f + expf(-a));
        stemp = btemp[h] * (2.f - sig);
    }
    __syncthreads();
    for (int e = tid; e < 2304; e += 256) {
        int c = e / 48, d = e % 48;
        sA[c][d] *= invq[c] * invk[d] * stemp;
    }
    __syncthreads();
    if (tid < 48) {
        float m = -1e30f;
        for (int d = 0; d < 48; d++) m = fmaxf(m, sA[tid][d]);
        float sum = 0.f;
        for (int d = 0; d < 48; d++) {
            float e_ = expf(sA[tid][d] - m);
            sA[tid][d] = e_;
            sum += e_;
        }
        float r = 1.f / sum;
        for (int d = 0; d < 48; d++)
            attn[h * 2304 + tid * 48 + d] = sA[tid][d] * r;
    }
}

// ---------------- K4: W_eff[o][j] = sum_c w_out[o][h*48+c] * attn[h][c][d]  (j=h*48+d)
__global__ __launch_bounds__(256) void k4_weff(const float* __restrict__ w_out,
                                               const float* __restrict__ attn,
                                               float* __restrict__ weff) {
    int e = blockIdx.x * 256 + threadIdx.x;  // < 36864
    int o = e / 192, j = e % 192;
    int h = j / 48, d = j % 48;
    const float* wr = w_out + o * 192 + h * 48;
    const float* ar = attn + h * 2304 + d;
    float s = 0.f;
    #pragma unroll
    for (int c = 0; c < 48; c++) s += wr[c] * ar[c * 48];
    weff[e] = s;
}

// ---------------- K5: out[o][n] = sum_j weff[o][j] * dw(qkv_pre[384+j])[n]
// grid (512 n-tiles of 128, 2 o-tiles of 96). v never materialized.
__global__ __launch_bounds__(256) void k5_out_gemm(const float* __restrict__ weff,
                                                   const float* __restrict__ qkv,
                                                   const float* __restrict__ wdw,
                                                   float* __restrict__ out) {
    __shared__ float Vs[8][128];
    __shared__ float Ws[8][96];
    __shared__ float wv[192 * 9];
    const int tid = threadIdx.x;
    const int nb = blockIdx.x;
    const int o_base = blockIdx.y * 96;
    const long n_base = (long)nb * 128;
    const int y = nb >> 1;
    const int x0 = (nb & 1) * 128;
    for (int e = tid; e < 1728; e += 256) wv[e] = wdw[384 * 9 + e];
    const int og = tid >> 5;   // 0..7 -> 12 contiguous o each
    const int ng = tid & 31;   // n = ng + 32*ii
    float acc[12][4];
    #pragma unroll
    for (int r = 0; r < 12; r++)
        #pragma unroll
        for (int ii = 0; ii < 4; ii++) acc[r][ii] = 0.f;

    for (int j0 = 0; j0 < 192; j0 += 8) {
        __syncthreads();
        for (int e = tid; e < 768; e += 256) {  // Ws[jj][oo]
            int oo = e >> 3, jj = e & 7;
            Ws[jj][oo] = weff[(o_base + oo) * 192 + j0 + jj];
        }
        for (int e = tid; e < 1024; e += 256) {  // Vs with fused dw
            int jj = e >> 7, p = e & 127;
            int j = j0 + jj;
            int x = x0 + p;
            const float* src = qkv + (long)(384 + j) * NPIX;
            const float* wp = &wv[j * 9];
            float a = 0.f;
            #pragma unroll
            for (int dy = -1; dy <= 1; dy++) {
                int yy = y + dy;
                if (yy < 0 || yy > 255) continue;
                #pragma unroll
                for (int dx = -1; dx <= 1; dx++) {
                    int xx = x + dx;
                    if (xx < 0 || xx > 255) continue;
                    a += wp[(dy + 1) * 3 + (dx + 1)] * src[yy * IW + xx];
                }
            }
            Vs[jj][p] = a;
        }
        __syncthreads();
        #pragma unroll
        for (int jj = 0; jj < 8; jj++) {
            float wr[12];
            *reinterpret_cast<float4*>(&wr[0]) = *reinterpret_cast<const float4*>(&Ws[jj][og * 12]);
            *reinterpret_cast<float4*>(&wr[4]) = *reinterpret_cast<const float4*>(&Ws[jj][og * 12 + 4]);
            *reinterpret_cast<float4*>(&wr[8]) = *reinterpret_cast<const float4*>(&Ws[jj][og * 12 + 8]);
            float vv[4];
            #pragma unroll
            for (int ii = 0; ii < 4; ii++) vv[ii] = Vs[jj][ng + 32 * ii];
            #pragma unroll
            for (int r = 0; r < 12; r++)
                #pragma unroll
                for (int ii = 0; ii < 4; ii++) acc[r][ii] += wr[r] * vv[ii];
        }
    }
    #pragma unroll
    for (int r = 0; r < 12; r++) {
        long row = o_base + og * 12 + r;
        #pragma unroll
        for (int ii = 0; ii < 4; ii++)
            out[row * NPIX + n_base + ng + 32 * ii] = acc[r][ii];
    }
}

extern "C" void kernel_launch(void* const* d_in, const int* in_sizes, int n_in,
                              void* d_out, int out_size, void* d_ws, size_t ws_size,
                              hipStream_t stream) {
    const float* x      = (const float*)d_in[0];
    const float* noise  = (const float*)d_in[1];
    const float* btemp  = (const float*)d_in[2];
    const float* w_nm1  = (const float*)d_in[3];
    const float* w_nm2  = (const float*)d_in[4];
    const float* w_qkv  = (const float*)d_in[5];
    const float* w_dw   = (const float*)d_in[6];
    const float* w_out  = (const float*)d_in[7];
    float* out = (float*)d_out;
    float* ws = (float*)d_ws;

    // pick gram chunk count based on available workspace (deterministic)
    long avail = (long)(ws_size / 4) - 37748736L;
    int nchk = 64;
    if (avail >= 9600L * 256 + 55680) nchk = 256;
    else if (avail >= 9600L * 128 + 55680) nchk = 128;
    const int rpc = 256 / nchk;  // image rows per chunk

    float* qkv_pre = ws;                        // 576*65536 = 37748736 floats
    float* Sp    = qkv_pre + 37748736;          // 4*nchk*2304
    float* sqq   = Sp + (long)4 * nchk * 2304;  // 192*nchk
    float* sqk   = sqq + (long)192 * nchk;      // 192*nchk
    float* S     = sqk + (long)192 * nchk;      // 9216
    float* sumsq = S + 9216;                    // 384
    float* attn  = sumsq + 384;                 // 9216
    float* weff  = attn + 9216;                 // 36864

    for (int b = 0; b < 2; b++) {
        const float* xb = x + (long)b * 192 * NPIX;
        float* outb = out + (long)b * 192 * NPIX;
        k1_qkv_gemm<<<dim3(256, 9), 256, 0, stream>>>(w_qkv, xb, qkv_pre);
        k2_gram<<<dim3(nchk, 4), 256, 0, stream>>>(qkv_pre, w_dw, Sp, sqq, sqk, nchk, rpc);
        k3a_reduce<<<38, 256, 0, stream>>>(Sp, sqq, sqk, S, sumsq, nchk);
        k3b_attn<<<4, 256, 0, stream>>>(S, sumsq, noise, btemp, w_nm1, w_nm2, attn, b);
        k4_weff<<<144, 256, 0, stream>>>(w_out, attn, weff);
        k5_out_gemm<<<dim3(512, 2), 256, 0, stream>>>(weff, qkv_pre, w_dw, outb);
    }
}

// Round 3
// 1303.157 us; speedup vs baseline: 1.9461x; 1.6225x over previous
//
#include <hip/hip_runtime.h>
#include <hip/hip_bf16.h>

#define NPIX 65536
#define IW 256

// ---------------- K1: out[m][n] = sum_k w[m*192+k] * x[k*NPIX+n]
// K=192 fixed. BM=64 BN=256 BK=8, 256 threads, 8x8 micro-tile.
// Used for qkv (M=576, grid.y=9) and for out-proj (M=192, grid.y=3).
__global__ __launch_bounds__(256) void k1_qkv_gemm(const float* __restrict__ w,
                                                   const float* __restrict__ x,
                                                   float* __restrict__ out) {
    __shared__ float As[8][64];
    __shared__ float Bs[8][256];
    const int tid = threadIdx.x;
    const int m_base = blockIdx.y * 64;
    const long n_base = (long)blockIdx.x * 256;
    const int tm = tid & 7;    // m group 0..7
    const int tn = tid >> 3;   // n group 0..31
    float acc[8][8];
    #pragma unroll
    for (int i = 0; i < 8; i++)
        #pragma unroll
        for (int j = 0; j < 8; j++) acc[i][j] = 0.f;

    for (int kc = 0; kc < 192; kc += 8) {
        __syncthreads();
        if (tid < 128) {  // stage A (64m x 8k), transposed into As[k][m]
            int mm = tid >> 1;
            int kq = (tid & 1) * 4;
            float4 v = *reinterpret_cast<const float4*>(w + (m_base + mm) * 192 + kc + kq);
            As[kq + 0][mm] = v.x; As[kq + 1][mm] = v.y;
            As[kq + 2][mm] = v.z; As[kq + 3][mm] = v.w;
        }
        #pragma unroll
        for (int e = 0; e < 2; e++) {  // stage B (8k x 256n) as float4
            int f4 = tid + 256 * e;
            int kk = f4 >> 6;
            int nn4 = f4 & 63;
            float4 v = *reinterpret_cast<const float4*>(x + (long)(kc + kk) * NPIX + n_base + nn4 * 4);
            *reinterpret_cast<float4*>(&Bs[kk][nn4 * 4]) = v;
        }
        __syncthreads();
        #pragma unroll
        for (int k = 0; k < 8; k++) {
            float a[8], bb[8];
            *reinterpret_cast<float4*>(&a[0]) = *reinterpret_cast<const float4*>(&As[k][tm * 8]);
            *reinterpret_cast<float4*>(&a[4]) = *reinterpret_cast<const float4*>(&As[k][tm * 8 + 4]);
            *reinterpret_cast<float4*>(&bb[0]) = *reinterpret_cast<const float4*>(&Bs[k][tn * 8]);
            *reinterpret_cast<float4*>(&bb[4]) = *reinterpret_cast<const float4*>(&Bs[k][tn * 8 + 4]);
            #pragma unroll
            for (int i = 0; i < 8; i++)
                #pragma unroll
                for (int j = 0; j < 8; j++) acc[i][j] += a[i] * bb[j];
        }
    }
    #pragma unroll
    for (int i = 0; i < 8; i++) {
        long row = m_base + tm * 8 + i;
        float* dst = out + row * NPIX + n_base + tn * 8;
        float4 v0 = {acc[i][0], acc[i][1], acc[i][2], acc[i][3]};
        float4 v1 = {acc[i][4], acc[i][5], acc[i][6], acc[i][7]};
        *reinterpret_cast<float4*>(dst) = v0;
        *reinterpret_cast<float4*>(dst + 4) = v1;
    }
}

// ---------------- K2: fused depthwise-3x3 + Gram partials + sumsq partials
// grid (nchk chunks, 4 heads); each chunk = rpc image rows; q,k never hit HBM.
// Sp layout: [h][48*48 element][chunk]  (chunk contiguous for coalesced reduce)
__global__ __launch_bounds__(256) void k2_gram(const float* __restrict__ qkv,
                                               const float* __restrict__ wdw,
                                               float* __restrict__ Sp,
                                               float* __restrict__ sqq,  // [192][nchk]
                                               float* __restrict__ sqk,
                                               int nchk, int rpc) {
    __shared__ float qs[48][132];
    __shared__ float ks[48][132];
    __shared__ float wl[96][9];
    const int tid = threadIdx.x;
    const int chunk = blockIdx.x;
    const int h = blockIdx.y;
    for (int e = tid; e < 96 * 9; e += 256) {
        int cl = e / 9, t = e % 9;
        int chg = (cl < 48) ? (h * 48 + cl) : (192 + h * 48 + (cl - 48));
        wl[cl][t] = wdw[chg * 9 + t];
    }
    float g[9];
    #pragma unroll
    for (int i = 0; i < 9; i++) g[i] = 0.f;
    float ss = 0.f;
    const int c0 = 3 * (tid >> 4);
    const int d0 = 3 * (tid & 15);
    const int y0 = chunk * rpc;
    const int nsub = rpc * 2;

    for (int sub = 0; sub < nsub; sub++) {
        int y = y0 + (sub >> 1);
        int x0 = (sub & 1) * 128;
        __syncthreads();
        for (int idx = tid; idx < 96 * 128; idx += 256) {
            int cl = idx >> 7, p = idx & 127;
            int x = x0 + p;
            int chg = (cl < 48) ? (h * 48 + cl) : (192 + h * 48 + (cl - 48));
            const float* src = qkv + (long)chg * NPIX;
            float a = 0.f;
            #pragma unroll
            for (int dy = -1; dy <= 1; dy++) {
                int yy = y + dy;
                if (yy < 0 || yy > 255) continue;
                #pragma unroll
                for (int dx = -1; dx <= 1; dx++) {
                    int xx = x + dx;
                    if (xx < 0 || xx > 255) continue;
                    a += wl[cl][(dy + 1) * 3 + (dx + 1)] * src[yy * IW + xx];
                }
            }
            if (cl < 48) qs[cl][p] = a; else ks[cl - 48][p] = a;
        }
        __syncthreads();
        #pragma unroll 4
        for (int p4 = 0; p4 < 32; p4++) {
            float4 qa[3], ka[3];
            #pragma unroll
            for (int i = 0; i < 3; i++) qa[i] = *reinterpret_cast<const float4*>(&qs[c0 + i][p4 * 4]);
            #pragma unroll
            for (int j = 0; j < 3; j++) ka[j] = *reinterpret_cast<const float4*>(&ks[d0 + j][p4 * 4]);
            #pragma unroll
            for (int i = 0; i < 3; i++)
                #pragma unroll
                for (int j = 0; j < 3; j++)
                    g[i * 3 + j] += qa[i].x * ka[j].x + qa[i].y * ka[j].y +
                                    qa[i].z * ka[j].z + qa[i].w * ka[j].w;
        }
        if (tid < 96) {
            const float* row = (tid < 48) ? &qs[tid][0] : &ks[tid - 48][0];
            for (int p4 = 0; p4 < 32; p4++) {
                float4 v = *reinterpret_cast<const float4*>(row + p4 * 4);
                ss += v.x * v.x + v.y * v.y + v.z * v.z + v.w * v.w;
            }
        }
    }
    #pragma unroll
    for (int i = 0; i < 3; i++)
        #pragma unroll
        for (int j = 0; j < 3; j++)
            Sp[((long)h * 2304 + (c0 + i) * 48 + (d0 + j)) * nchk + chunk] = g[i * 3 + j];
    if (tid < 48) sqq[(h * 48 + tid) * nchk + chunk] = ss;
    else if (tid < 96) sqk[(h * 48 + (tid - 48)) * nchk + chunk] = ss;
}

// ---------------- K3a: wave-per-element reduce of Gram + sumsq partials
__global__ __launch_bounds__(256) void k3a_reduce(const float* __restrict__ Sp,
                                                  const float* __restrict__ sqq,
                                                  const float* __restrict__ sqk,
                                                  float* __restrict__ S,      // [4][2304]
                                                  float* __restrict__ sumsq,  // [384]
                                                  int nchk) {
    const int wid = threadIdx.x >> 6, lane = threadIdx.x & 63;
    const int e = blockIdx.x * 4 + wid;
    const float* p;
    if (e < 9216) {
        p = Sp + (long)e * nchk;
    } else {
        int c = e - 9216;
        if (c >= 384) return;
        p = (c < 192) ? (sqq + (long)c * nchk) : (sqk + (long)(c - 192) * nchk);
    }
    float s = 0.f;
    for (int i = lane; i < nchk; i += 64) s += p[i];
    #pragma unroll
    for (int m = 32; m; m >>= 1) s += __shfl_xor(s, m, 64);
    if (lane == 0) {
        if (e < 9216) S[e] = s;
        else sumsq[e - 9216] = s;
    }
}

// ---------------- K3b: norms, noise MLP, softmax -> attn[4][48][48]
__global__ __launch_bounds__(256) void k3b_attn(const float* __restrict__ S,
                                                const float* __restrict__ sumsq,
                                                const float* __restrict__ noise,
                                                const float* __restrict__ btemp,
                                                const float* __restrict__ w_nm1,
                                                const float* __restrict__ w_nm2,
                                                float* __restrict__ attn, int b) {
    __shared__ float sA[48][49];
    __shared__ float invq[48], invk[48];
    __shared__ float stemp;
    const int h = blockIdx.x, tid = threadIdx.x;
    for (int e = tid; e < 2304; e += 256)
        sA[e / 48][e % 48] = S[h * 2304 + e];
    if (tid < 96) {
        float s = (tid < 48) ? sumsq[h * 48 + tid] : sumsq[192 + h * 48 + (tid - 48)];
        float inv = 1.f / fmaxf(sqrtf(s), 1e-12f);
        if (tid < 48) invq[tid] = inv; else invk[tid - 48] = inv;
    }
    if (tid == 0) {
        float nz = noise[b];
        float a = 0.f;
        for (int i = 0; i < 48; i++) {
            float t = w_nm1[i] * nz;
            t = (t >= 0.f) ? t : 0.2f * t;
            a += w_nm2[h * 48 + i] * t;
        }
        float sig = 1.f / (1.f + expf(-a));
        stemp = btemp[h] * (2.f - sig);
    }
    __syncthreads();
    for (int e = tid; e < 2304; e += 256) {
        int c = e / 48, d = e % 48;
        sA[c][d] *= invq[c] * invk[d] * stemp;
    }
    __syncthreads();
    if (tid < 48) {
        float m = -1e30f;
        for (int d = 0; d < 48; d++) m = fmaxf(m, sA[tid][d]);
        float sum = 0.f;
        for (int d = 0; d < 48; d++) {
            float e_ = expf(sA[tid][d] - m);
            sA[tid][d] = e_;
            sum += e_;
        }
        float r = 1.f / sum;
        for (int d = 0; d < 48; d++)
            attn[h * 2304 + tid * 48 + d] = sA[tid][d] * r;
    }
}

// ---------------- K4: W_eff[o][j] = sum_c w_out[o][h*48+c] * attn[h][c][d]  (j=h*48+d)
__global__ __launch_bounds__(256) void k4_weff(const float* __restrict__ w_out,
                                               const float* __restrict__ attn,
                                               float* __restrict__ weff) {
    int e = blockIdx.x * 256 + threadIdx.x;  // < 36864
    int o = e / 192, j = e % 192;
    int h = j / 48, d = j % 48;
    const float* wr = w_out + o * 192 + h * 48;
    const float* ar = attn + h * 2304 + d;
    float s = 0.f;
    #pragma unroll
    for (int c = 0; c < 48; c++) s += wr[c] * ar[c * 48];
    weff[e] = s;
}

// ---------------- K5a: V[j][n] = dwconv3x3(qkv_pre[384+j])[n]  (streaming)
// grid (64 row-groups, 192 channels); block stages 6 rows in LDS, 4 px/thread.
__global__ __launch_bounds__(256) void k5a_dwconv(const float* __restrict__ qkv,
                                                  const float* __restrict__ wdw,
                                                  float* __restrict__ vbuf) {
    __shared__ float rows[6][IW];
    const int tid = threadIdx.x;
    const int j = blockIdx.y;
    const int y0 = blockIdx.x * 4;
    const float* src = qkv + (long)(384 + j) * NPIX;
    float wv[9];
    #pragma unroll
    for (int t = 0; t < 9; t++) wv[t] = wdw[(384 + j) * 9 + t];
    for (int e = tid; e < 6 * IW; e += 256) {
        int r = e >> 8, xx = e & 255;
        int yy = y0 - 1 + r;
        rows[r][xx] = (yy >= 0 && yy <= 255) ? src[yy * IW + xx] : 0.f;
    }
    __syncthreads();
    const int x = tid;
    #pragma unroll
    for (int r = 0; r < 4; r++) {
        float a = 0.f;
        #pragma unroll
        for (int dy = 0; dy < 3; dy++) {
            const float* rw = rows[r + dy];
            if (x > 0)   a += wv[dy * 3 + 0] * rw[x - 1];
                         a += wv[dy * 3 + 1] * rw[x];
            if (x < 255) a += wv[dy * 3 + 2] * rw[x + 1];
        }
        vbuf[(long)j * NPIX + (y0 + r) * IW + x] = a;
    }
}

extern "C" void kernel_launch(void* const* d_in, const int* in_sizes, int n_in,
                              void* d_out, int out_size, void* d_ws, size_t ws_size,
                              hipStream_t stream) {
    const float* x      = (const float*)d_in[0];
    const float* noise  = (const float*)d_in[1];
    const float* btemp  = (const float*)d_in[2];
    const float* w_nm1  = (const float*)d_in[3];
    const float* w_nm2  = (const float*)d_in[4];
    const float* w_qkv  = (const float*)d_in[5];
    const float* w_dw   = (const float*)d_in[6];
    const float* w_out  = (const float*)d_in[7];
    float* out = (float*)d_out;
    float* ws = (float*)d_ws;

    // pick gram chunk count based on available workspace (deterministic)
    long avail = (long)(ws_size / 4) - 37748736L;
    int nchk = 64;
    if (avail >= 9600L * 256 + 55680) nchk = 256;
    else if (avail >= 9600L * 128 + 55680) nchk = 128;
    const int rpc = 256 / nchk;  // image rows per chunk

    float* qkv_pre = ws;                        // 576*65536 floats
    float* vbuf = qkv_pre;                      // V overwrites dead q/k region after k2
    float* Sp    = qkv_pre + 37748736;          // 9216*nchk
    float* sqq   = Sp + (long)9216 * nchk;      // 192*nchk
    float* sqk   = sqq + (long)192 * nchk;      // 192*nchk
    float* S     = sqk + (long)192 * nchk;      // 9216
    float* sumsq = S + 9216;                    // 384
    float* attn  = sumsq + 384;                 // 9216
    float* weff  = attn + 9216;                 // 36864

    for (int b = 0; b < 2; b++) {
        const float* xb = x + (long)b * 192 * NPIX;
        float* outb = out + (long)b * 192 * NPIX;
        k1_qkv_gemm<<<dim3(256, 9), 256, 0, stream>>>(w_qkv, xb, qkv_pre);
        k2_gram<<<dim3(nchk, 4), 256, 0, stream>>>(qkv_pre, w_dw, Sp, sqq, sqk, nchk, rpc);
        k3a_reduce<<<2400, 256, 0, stream>>>(Sp, sqq, sqk, S, sumsq, nchk);
        k3b_attn<<<4, 256, 0, stream>>>(S, sumsq, noise, btemp, w_nm1, w_nm2, attn, b);
        k4_weff<<<144, 256, 0, stream>>>(w_out, attn, weff);
        // k5a AFTER k2: overwrites channels 0..191 (q region, dead after k2)
        k5a_dwconv<<<dim3(64, 192), 256, 0, stream>>>(qkv_pre, w_dw, vbuf);
        k1_qkv_gemm<<<dim3(256, 3), 256, 0, stream>>>(weff, vbuf, outb);
    }
}

// Round 4
// 750.466 us; speedup vs baseline: 3.3794x; 1.7365x over previous
//
#include <hip/hip_runtime.h>
#include <hip/hip_bf16.h>

#define NPIX 65536
#define IW 256

typedef unsigned short ushort_t;

__device__ __forceinline__ float b2f(ushort_t u) {
    union { unsigned int i; float f; } v;
    v.i = ((unsigned int)u) << 16;
    return v.f;
}
__device__ __forceinline__ ushort_t f2b(float f) {
    __hip_bfloat16 h = __float2bfloat16(f);
    return *reinterpret_cast<ushort_t*>(&h);
}

// ---------------- K1b: qkvb[m][n] = sum_k w[m*192+k] * x[k*NPIX+n], output bf16
__global__ __launch_bounds__(256) void k1b_qkv_gemm(const float* __restrict__ w,
                                                    const float* __restrict__ x,
                                                    ushort_t* __restrict__ out) {
    __shared__ float As[8][64];
    __shared__ float Bs[8][256];
    const int tid = threadIdx.x;
    const int m_base = blockIdx.y * 64;
    const long n_base = (long)blockIdx.x * 256;
    const int tm = tid & 7;
    const int tn = tid >> 3;
    float acc[8][8];
    #pragma unroll
    for (int i = 0; i < 8; i++)
        #pragma unroll
        for (int j = 0; j < 8; j++) acc[i][j] = 0.f;

    for (int kc = 0; kc < 192; kc += 8) {
        __syncthreads();
        if (tid < 128) {
            int mm = tid >> 1;
            int kq = (tid & 1) * 4;
            float4 v = *reinterpret_cast<const float4*>(w + (m_base + mm) * 192 + kc + kq);
            As[kq + 0][mm] = v.x; As[kq + 1][mm] = v.y;
            As[kq + 2][mm] = v.z; As[kq + 3][mm] = v.w;
        }
        #pragma unroll
        for (int e = 0; e < 2; e++) {
            int f4 = tid + 256 * e;
            int kk = f4 >> 6;
            int nn4 = f4 & 63;
            float4 v = *reinterpret_cast<const float4*>(x + (long)(kc + kk) * NPIX + n_base + nn4 * 4);
            *reinterpret_cast<float4*>(&Bs[kk][nn4 * 4]) = v;
        }
        __syncthreads();
        #pragma unroll
        for (int k = 0; k < 8; k++) {
            float a[8], bb[8];
            *reinterpret_cast<float4*>(&a[0]) = *reinterpret_cast<const float4*>(&As[k][tm * 8]);
            *reinterpret_cast<float4*>(&a[4]) = *reinterpret_cast<const float4*>(&As[k][tm * 8 + 4]);
            *reinterpret_cast<float4*>(&bb[0]) = *reinterpret_cast<const float4*>(&Bs[k][tn * 8]);
            *reinterpret_cast<float4*>(&bb[4]) = *reinterpret_cast<const float4*>(&Bs[k][tn * 8 + 4]);
            #pragma unroll
            for (int i = 0; i < 8; i++)
                #pragma unroll
                for (int j = 0; j < 8; j++) acc[i][j] += a[i] * bb[j];
        }
    }
    #pragma unroll
    for (int i = 0; i < 8; i++) {
        long row = m_base + tm * 8 + i;
        ushort_t* dst = out + row * (long)NPIX + n_base + tn * 8;
        ushort4 v0 = make_ushort4(f2b(acc[i][0]), f2b(acc[i][1]), f2b(acc[i][2]), f2b(acc[i][3]));
        ushort4 v1 = make_ushort4(f2b(acc[i][4]), f2b(acc[i][5]), f2b(acc[i][6]), f2b(acc[i][7]));
        *reinterpret_cast<ushort4*>(dst) = v0;
        *reinterpret_cast<ushort4*>(dst + 4) = v1;
    }
}

// ---------------- KDW: dwb[j] = dwconv3x3(qkvb[j]), bf16 in/out, all 576 ch
__global__ __launch_bounds__(256) void kdw_conv(const ushort_t* __restrict__ qkvb,
                                                const float* __restrict__ wdw,
                                                ushort_t* __restrict__ dwb) {
    __shared__ ushort_t rows[6][IW];
    const int tid = threadIdx.x;
    const int j = blockIdx.y;
    const int y0 = blockIdx.x * 4;
    const ushort_t* src = qkvb + (long)j * NPIX;
    float wv[9];
    #pragma unroll
    for (int t = 0; t < 9; t++) wv[t] = wdw[j * 9 + t];
    for (int e = tid; e < 6 * 128; e += 256) {
        int r = e >> 7, xh = e & 127;
        int yy = y0 - 1 + r;
        ushort2 val = (yy >= 0 && yy <= 255)
            ? *reinterpret_cast<const ushort2*>(src + yy * IW + xh * 2)
            : make_ushort2(0, 0);
        *reinterpret_cast<ushort2*>(&rows[r][xh * 2]) = val;
    }
    __syncthreads();
    const int x = tid;
    #pragma unroll
    for (int r = 0; r < 4; r++) {
        float a = 0.f;
        #pragma unroll
        for (int dy = 0; dy < 3; dy++) {
            const ushort_t* rw = rows[r + dy];
            if (x > 0)   a += wv[dy * 3 + 0] * b2f(rw[x - 1]);
                         a += wv[dy * 3 + 1] * b2f(rw[x]);
            if (x < 255) a += wv[dy * 3 + 2] * b2f(rw[x + 1]);
        }
        dwb[(long)j * NPIX + (y0 + r) * IW + x] = f2b(a);
    }
}

// ---------------- K2: Gram partials from materialized bf16 dw(q),dw(k)
__global__ __launch_bounds__(256) void k2_gram(const ushort_t* __restrict__ dwb,
                                               float* __restrict__ Sp,
                                               float* __restrict__ sqq,
                                               float* __restrict__ sqk,
                                               int nchk, int nsub) {
    __shared__ ushort_t qs[48][264];
    __shared__ ushort_t ks[48][264];
    const int tid = threadIdx.x;
    const int chunk = blockIdx.x;
    const int h = blockIdx.y;
    float g[9];
    #pragma unroll
    for (int i = 0; i < 9; i++) g[i] = 0.f;
    float ss = 0.f;
    const int c0 = 3 * (tid >> 4);
    const int d0 = 3 * (tid & 15);

    for (int sub = 0; sub < nsub; sub++) {
        const long p0 = ((long)chunk * nsub + sub) * 256;
        __syncthreads();
        for (int e = tid; e < 96 * 64; e += 256) {
            int cl = e >> 6, p4 = e & 63;
            int chg = (cl < 48) ? (h * 48 + cl) : (192 + h * 48 + (cl - 48));
            ushort4 v = *reinterpret_cast<const ushort4*>(dwb + (long)chg * NPIX + p0 + p4 * 4);
            if (cl < 48) *reinterpret_cast<ushort4*>(&qs[cl][p4 * 4]) = v;
            else         *reinterpret_cast<ushort4*>(&ks[cl - 48][p4 * 4]) = v;
        }
        __syncthreads();
        #pragma unroll 4
        for (int p4 = 0; p4 < 64; p4++) {
            float qa[3][4], ka[3][4];
            #pragma unroll
            for (int i = 0; i < 3; i++) {
                ushort4 v = *reinterpret_cast<const ushort4*>(&qs[c0 + i][p4 * 4]);
                qa[i][0] = b2f(v.x); qa[i][1] = b2f(v.y); qa[i][2] = b2f(v.z); qa[i][3] = b2f(v.w);
            }
            #pragma unroll
            for (int jj = 0; jj < 3; jj++) {
                ushort4 v = *reinterpret_cast<const ushort4*>(&ks[d0 + jj][p4 * 4]);
                ka[jj][0] = b2f(v.x); ka[jj][1] = b2f(v.y); ka[jj][2] = b2f(v.z); ka[jj][3] = b2f(v.w);
            }
            #pragma unroll
            for (int i = 0; i < 3; i++)
                #pragma unroll
                for (int jj = 0; jj < 3; jj++)
                    g[i * 3 + jj] += qa[i][0] * ka[jj][0] + qa[i][1] * ka[jj][1] +
                                     qa[i][2] * ka[jj][2] + qa[i][3] * ka[jj][3];
        }
        if (tid < 96) {
            const ushort_t* row = (tid < 48) ? &qs[tid][0] : &ks[tid - 48][0];
            for (int p = 0; p < 256; p += 4) {
                ushort4 v = *reinterpret_cast<const ushort4*>(row + p);
                float a = b2f(v.x), bq = b2f(v.y), c = b2f(v.z), d = b2f(v.w);
                ss += a * a + bq * bq + c * c + d * d;
            }
        }
    }
    #pragma unroll
    for (int i = 0; i < 3; i++)
        #pragma unroll
        for (int jj = 0; jj < 3; jj++)
            Sp[((long)h * 2304 + (c0 + i) * 48 + (d0 + jj)) * nchk + chunk] = g[i * 3 + jj];
    if (tid < 48) sqq[(h * 48 + tid) * nchk + chunk] = ss;
    else if (tid < 96) sqk[(h * 48 + (tid - 48)) * nchk + chunk] = ss;
}

// ---------------- K3a: wave-per-element reduce
__global__ __launch_bounds__(256) void k3a_reduce(const float* __restrict__ Sp,
                                                  const float* __restrict__ sqq,
                                                  const float* __restrict__ sqk,
                                                  float* __restrict__ S,
                                                  float* __restrict__ sumsq,
                                                  int nchk) {
    const int wid = threadIdx.x >> 6, lane = threadIdx.x & 63;
    const int e = blockIdx.x * 4 + wid;
    const float* p;
    if (e < 9216) {
        p = Sp + (long)e * nchk;
    } else {
        int c = e - 9216;
        if (c >= 384) return;
        p = (c < 192) ? (sqq + (long)c * nchk) : (sqk + (long)(c - 192) * nchk);
    }
    float s = 0.f;
    for (int i = lane; i < nchk; i += 64) s += p[i];
    #pragma unroll
    for (int m = 32; m; m >>= 1) s += __shfl_xor(s, m, 64);
    if (lane == 0) {
        if (e < 9216) S[e] = s;
        else sumsq[e - 9216] = s;
    }
}

// ---------------- K3b: norms, noise MLP, softmax -> attn[4][48][48]
__global__ __launch_bounds__(256) void k3b_attn(const float* __restrict__ S,
                                                const float* __restrict__ sumsq,
                                                const float* __restrict__ noise,
                                                const float* __restrict__ btemp,
                                                const float* __restrict__ w_nm1,
                                                const float* __restrict__ w_nm2,
                                                float* __restrict__ attn, int b) {
    __shared__ float sA[48][49];
    __shared__ float invq[48], invk[48];
    __shared__ float stemp;
    const int h = blockIdx.x, tid = threadIdx.x;
    for (int e = tid; e < 2304; e += 256)
        sA[e / 48][e % 48] = S[h * 2304 + e];
    if (tid < 96) {
        float s = (tid < 48) ? sumsq[h * 48 + tid] : sumsq[192 + h * 48 + (tid - 48)];
        float inv = 1.f / fmaxf(sqrtf(s), 1e-12f);
        if (tid < 48) invq[tid] = inv; else invk[tid - 48] = inv;
    }
    if (tid == 0) {
        float nz = noise[b];
        float a = 0.f;
        for (int i = 0; i < 48; i++) {
            float t = w_nm1[i] * nz;
            t = (t >= 0.f) ? t : 0.2f * t;
            a += w_nm2[h * 48 + i] * t;
        }
        float sig = 1.f / (1.f + expf(-a));
        stemp = btemp[h] * (2.f - sig);
    }
    __syncthreads();
    for (int e = tid; e < 2304; e += 256) {
        int c = e / 48, d = e % 48;
        sA[c][d] *= invq[c] * invk[d] * stemp;
    }
    __syncthreads();
    if (tid < 48) {
        float m = -1e30f;
        for (int d = 0; d < 48; d++) m = fmaxf(m, sA[tid][d]);
        float sum = 0.f;
        for (int d = 0; d < 48; d++) {
            float e_ = expf(sA[tid][d] - m);
            sA[tid][d] = e_;
            sum += e_;
        }
        float r = 1.f / sum;
        for (int d = 0; d < 48; d++)
            attn[h * 2304 + tid * 48 + d] = sA[tid][d] * r;
    }
}

// ---------------- K4: W_eff[o][j] = sum_c w_out[o][h*48+c] * attn[h][c][d]
__global__ __launch_bounds__(256) void k4_weff(const float* __restrict__ w_out,
                                               const float* __restrict__ attn,
                                               float* __restrict__ weff) {
    int e = blockIdx.x * 256 + threadIdx.x;
    int o = e / 192, j = e % 192;
    int h = j / 48, d = j % 48;
    const float* wr = w_out + o * 192 + h * 48;
    const float* ar = attn + h * 2304 + d;
    float s = 0.f;
    #pragma unroll
    for (int c = 0; c < 48; c++) s += wr[c] * ar[c * 48];
    weff[e] = s;
}

// ---------------- K5b: out[o][n] = sum_j weff[o][j] * V[j][n], V bf16
__global__ __launch_bounds__(256) void k5b_out_gemm(const float* __restrict__ w,
                                                    const ushort_t* __restrict__ vb,
                                                    float* __restrict__ out) {
    __shared__ float As[8][64];
    __shared__ float Bs[8][256];
    const int tid = threadIdx.x;
    const int m_base = blockIdx.y * 64;
    const long n_base = (long)blockIdx.x * 256;
    const int tm = tid & 7;
    const int tn = tid >> 3;
    float acc[8][8];
    #pragma unroll
    for (int i = 0; i < 8; i++)
        #pragma unroll
        for (int j = 0; j < 8; j++) acc[i][j] = 0.f;

    for (int kc = 0; kc < 192; kc += 8) {
        __syncthreads();
        if (tid < 128) {
            int mm = tid >> 1;
            int kq = (tid & 1) * 4;
            float4 v = *reinterpret_cast<const float4*>(w + (m_base + mm) * 192 + kc + kq);
            As[kq + 0][mm] = v.x; As[kq + 1][mm] = v.y;
            As[kq + 2][mm] = v.z; As[kq + 3][mm] = v.w;
        }
        #pragma unroll
        for (int e = 0; e < 2; e++) {
            int u4 = tid + 256 * e;
            int kk = u4 >> 6;
            int nn4 = u4 & 63;
            ushort4 v = *reinterpret_cast<const ushort4*>(vb + (long)(kc + kk) * NPIX + n_base + nn4 * 4);
            float4 f = {b2f(v.x), b2f(v.y), b2f(v.z), b2f(v.w)};
            *reinterpret_cast<float4*>(&Bs[kk][nn4 * 4]) = f;
        }
        __syncthreads();
        #pragma unroll
        for (int k = 0; k < 8; k++) {
            float a[8], bb[8];
            *reinterpret_cast<float4*>(&a[0]) = *reinterpret_cast<const float4*>(&As[k][tm * 8]);
            *reinterpret_cast<float4*>(&a[4]) = *reinterpret_cast<const float4*>(&As[k][tm * 8 + 4]);
            *reinterpret_cast<float4*>(&bb[0]) = *reinterpret_cast<const float4*>(&Bs[k][tn * 8]);
            *reinterpret_cast<float4*>(&bb[4]) = *reinterpret_cast<const float4*>(&Bs[k][tn * 8 + 4]);
            #pragma unroll
            for (int i = 0; i < 8; i++)
                #pragma unroll
                for (int j = 0; j < 8; j++) acc[i][j] += a[i] * bb[j];
        }
    }
    #pragma unroll
    for (int i = 0; i < 8; i++) {
        long row = m_base + tm * 8 + i;
        float* dst = out + row * NPIX + n_base + tn * 8;
        float4 v0 = {acc[i][0], acc[i][1], acc[i][2], acc[i][3]};
        float4 v1 = {acc[i][4], acc[i][5], acc[i][6], acc[i][7]};
        *reinterpret_cast<float4*>(dst) = v0;
        *reinterpret_cast<float4*>(dst + 4) = v1;
    }
}

extern "C" void kernel_launch(void* const* d_in, const int* in_sizes, int n_in,
                              void* d_out, int out_size, void* d_ws, size_t ws_size,
                              hipStream_t stream) {
    const float* x      = (const float*)d_in[0];
    const float* noise  = (const float*)d_in[1];
    const float* btemp  = (const float*)d_in[2];
    const float* w_nm1  = (const float*)d_in[3];
    const float* w_nm2  = (const float*)d_in[4];
    const float* w_qkv  = (const float*)d_in[5];
    const float* w_dw   = (const float*)d_in[6];
    const float* w_out  = (const float*)d_in[7];
    float* out = (float*)d_out;
    float* ws = (float*)d_ws;

    // workspace-adaptive Sp chunk count (deterministic; ws_size constant)
    int nchk = ((long)(ws_size / 4) >= 40262016L) ? 256 : 64;
    const int nsub = 256 / nchk;

    // layout (float-slot offsets):
    // [0, 18874368)            qkvb  : 576*65536 bf16
    // [18874368, 37748736)     dwb   : 576*65536 bf16
    // [37748736, ...)          Sp, sqq, sqk, S, sumsq, attn, weff (fp32)
    ushort_t* qkvb = (ushort_t*)ws;
    ushort_t* dwb  = qkvb + (long)576 * NPIX;
    float* Sp    = ws + 37748736;
    float* sqq   = Sp + (long)9216 * nchk;
    float* sqk   = sqq + (long)192 * nchk;
    float* S     = sqk + (long)192 * nchk;
    float* sumsq = S + 9216;
    float* attn  = sumsq + 384;
    float* weff  = attn + 9216;
    const ushort_t* vb = dwb + (long)384 * NPIX;

    for (int b = 0; b < 2; b++) {
        const float* xb = x + (long)b * 192 * NPIX;
        float* outb = out + (long)b * 192 * NPIX;
        k1b_qkv_gemm<<<dim3(256, 9), 256, 0, stream>>>(w_qkv, xb, qkvb);
        kdw_conv<<<dim3(64, 576), 256, 0, stream>>>(qkvb, w_dw, dwb);
        k2_gram<<<dim3(nchk, 4), 256, 0, stream>>>(dwb, Sp, sqq, sqk, nchk, nsub);
        k3a_reduce<<<2400, 256, 0, stream>>>(Sp, sqq, sqk, S, sumsq, nchk);
        k3b_attn<<<4, 256, 0, stream>>>(S, sumsq, noise, btemp, w_nm1, w_nm2, attn, b);
        k4_weff<<<144, 256, 0, stream>>>(w_out, attn, weff);
        k5b_out_gemm<<<dim3(256, 3), 256, 0, stream>>>(weff, vb, outb);
    }
}

// Round 5
// 620.420 us; speedup vs baseline: 4.0878x; 1.2096x over previous
//
#include <hip/hip_runtime.h>
#include <hip/hip_bf16.h>

#define NPIX 65536
#define IW 256

typedef unsigned short ushort_t;
typedef __attribute__((ext_vector_type(8))) short bf16x8;
typedef __attribute__((ext_vector_type(4))) float f32x4;

__device__ __forceinline__ float b2f(ushort_t u) {
    union { unsigned int i; float f; } v;
    v.i = ((unsigned int)u) << 16;
    return v.f;
}
__device__ __forceinline__ ushort_t f2b(float f) {
    __hip_bfloat16 h = __float2bfloat16(f);
    return *reinterpret_cast<ushort_t*>(&h);
}

// ---------------- KT: xT[n][200] bf16 <- transpose of x fp32 [192][65536]
// block handles 64 n-columns; LDS tile [192][66] (pad 66 -> conflict-free col reads)
__global__ __launch_bounds__(256) void kT_transpose(const float* __restrict__ x,
                                                    ushort_t* __restrict__ xT) {
    __shared__ ushort_t Ls[192][66];
    const int tid = threadIdx.x;
    const long n0 = (long)blockIdx.x * 64;
    #pragma unroll
    for (int i = 0; i < 24; i++) {           // 192 rows x 32 float2
        int e = tid + i * 256;
        int k = e >> 5, n2 = e & 31;
        float2 v = *reinterpret_cast<const float2*>(x + (long)k * NPIX + n0 + n2 * 2);
        ushort2 o = make_ushort2(f2b(v.x), f2b(v.y));
        *reinterpret_cast<ushort2*>(&Ls[k][n2 * 2]) = o;
    }
    __syncthreads();
    const int n = tid >> 2, seg = tid & 3;
    const int kb = seg * 48;
    ushort_t* dst = xT + (n0 + n) * 200 + kb;
    #pragma unroll
    for (int w = 0; w < 6; w++) {
        unsigned int p0 = (unsigned int)Ls[kb + w * 8 + 0][n] | ((unsigned int)Ls[kb + w * 8 + 1][n] << 16);
        unsigned int p1 = (unsigned int)Ls[kb + w * 8 + 2][n] | ((unsigned int)Ls[kb + w * 8 + 3][n] << 16);
        unsigned int p2 = (unsigned int)Ls[kb + w * 8 + 4][n] | ((unsigned int)Ls[kb + w * 8 + 5][n] << 16);
        unsigned int p3 = (unsigned int)Ls[kb + w * 8 + 6][n] | ((unsigned int)Ls[kb + w * 8 + 7][n] << 16);
        *reinterpret_cast<int4*>(dst + w * 8) = make_int4(p0, p1, p2, p3);
    }
    if (seg == 3)  // zero the pad k=192..199
        *reinterpret_cast<int4*>(xT + (n0 + n) * 200 + 192) = make_int4(0, 0, 0, 0);
}

// ---------------- KGEMM (MFMA bf16): C[m][n] = sum_k A[m][k] * BT[n][k]
// A: [M][192] (fp32 if !A_BF16 else bf16); BT: [65536][200] bf16 padded rows.
// grid (M/64, 512): m fast-varying so m-blocks sharing a B-tile co-schedule (L2).
// block 64m x 128n, 4 waves, wave = 64m x 32n, K=192 staged once.
template<int A_BF16, int OUT_BF16>
__global__ __launch_bounds__(256) void kgemm_mfma(const void* __restrict__ Aptr,
                                                  const ushort_t* __restrict__ BT,
                                                  void* __restrict__ Cout) {
    __shared__ ushort_t As[64 * 200];
    __shared__ ushort_t Bs[128 * 200];
    const int tid = threadIdx.x;
    const int lane = tid & 63;
    const int wave = tid >> 6;
    const int m_base = blockIdx.x * 64;
    const long n_base = (long)blockIdx.y * 128;

    // stage A tile (64 x 192 -> padded 200)
    #pragma unroll
    for (int i = 0; i < 12; i++) {
        int c = tid + i * 256;               // 64*48 float4/ushort4 chunks
        int m = c / 48, k4 = c % 48;
        if (A_BF16) {
            const ushort_t* A = (const ushort_t*)Aptr;
            ushort4 v = *reinterpret_cast<const ushort4*>(A + (long)(m_base + m) * 192 + k4 * 4);
            *reinterpret_cast<ushort4*>(&As[m * 200 + k4 * 4]) = v;
        } else {
            const float* A = (const float*)Aptr;
            float4 v = *reinterpret_cast<const float4*>(A + (long)(m_base + m) * 192 + k4 * 4);
            ushort4 o = make_ushort4(f2b(v.x), f2b(v.y), f2b(v.z), f2b(v.w));
            *reinterpret_cast<ushort4*>(&As[m * 200 + k4 * 4]) = o;
        }
    }
    // stage B tile: 128 rows x 400B = 51200B contiguous from BT
    {
        const ushort_t* srcbase = BT + n_base * 200;
        #pragma unroll
        for (int i = 0; i < 13; i++) {
            int c = tid + i * 256;           // 16B chunks, 3200 total
            if (c < 3200) {
                int4 v = *reinterpret_cast<const int4*>(srcbase + c * 8);
                *reinterpret_cast<int4*>(&Bs[c * 8]) = v;
            }
        }
    }
    __syncthreads();

    const int r15 = lane & 15;
    const int g8 = (lane >> 4) * 8;
    const int nw = wave * 32;
    f32x4 acc[4][2];
    #pragma unroll
    for (int mi = 0; mi < 4; mi++)
        #pragma unroll
        for (int ni = 0; ni < 2; ni++)
            acc[mi][ni] = (f32x4){0.f, 0.f, 0.f, 0.f};

    #pragma unroll
    for (int kk = 0; kk < 192; kk += 32) {
        bf16x8 a[4], b[2];
        #pragma unroll
        for (int mi = 0; mi < 4; mi++)
            a[mi] = *reinterpret_cast<const bf16x8*>(&As[(mi * 16 + r15) * 200 + kk + g8]);
        #pragma unroll
        for (int ni = 0; ni < 2; ni++)
            b[ni] = *reinterpret_cast<const bf16x8*>(&Bs[(nw + ni * 16 + r15) * 200 + kk + g8]);
        #pragma unroll
        for (int mi = 0; mi < 4; mi++)
            #pragma unroll
            for (int ni = 0; ni < 2; ni++)
                acc[mi][ni] = __builtin_amdgcn_mfma_f32_16x16x32_bf16(a[mi], b[ni], acc[mi][ni], 0, 0, 0);
    }

    const int gq = (lane >> 4) * 4;
    #pragma unroll
    for (int mi = 0; mi < 4; mi++)
        #pragma unroll
        for (int ni = 0; ni < 2; ni++)
            #pragma unroll
            for (int r = 0; r < 4; r++) {
                long m = m_base + mi * 16 + gq + r;
                long n = n_base + nw + ni * 16 + r15;
                if (OUT_BF16) ((ushort_t*)Cout)[m * NPIX + n] = f2b(acc[mi][ni][r]);
                else          ((float*)Cout)[m * NPIX + n] = acc[mi][ni][r];
            }
}

// ---------------- KDW: dwb[j] = dwconv3x3(qkvb[j]), bf16, q/k channels (0..383)
__global__ __launch_bounds__(256) void kdw_conv(const ushort_t* __restrict__ qkvb,
                                                const float* __restrict__ wdw,
                                                ushort_t* __restrict__ dwb) {
    __shared__ ushort_t rows[6][IW];
    const int tid = threadIdx.x;
    const int j = blockIdx.y;
    const int y0 = blockIdx.x * 4;
    const ushort_t* src = qkvb + (long)j * NPIX;
    float wv[9];
    #pragma unroll
    for (int t = 0; t < 9; t++) wv[t] = wdw[j * 9 + t];
    for (int e = tid; e < 6 * 128; e += 256) {
        int r = e >> 7, xh = e & 127;
        int yy = y0 - 1 + r;
        ushort2 val = (yy >= 0 && yy <= 255)
            ? *reinterpret_cast<const ushort2*>(src + yy * IW + xh * 2)
            : make_ushort2(0, 0);
        *reinterpret_cast<ushort2*>(&rows[r][xh * 2]) = val;
    }
    __syncthreads();
    const int x = tid;
    #pragma unroll
    for (int r = 0; r < 4; r++) {
        float a = 0.f;
        #pragma unroll
        for (int dy = 0; dy < 3; dy++) {
            const ushort_t* rw = rows[r + dy];
            if (x > 0)   a += wv[dy * 3 + 0] * b2f(rw[x - 1]);
                         a += wv[dy * 3 + 1] * b2f(rw[x]);
            if (x < 255) a += wv[dy * 3 + 2] * b2f(rw[x + 1]);
        }
        dwb[(long)j * NPIX + (y0 + r) * IW + x] = f2b(a);
    }
}

// ---------------- KTV: fused v-channel dwconv3x3 + transpose -> vT[n][200] bf16
// block = 1 image row y, 32 pixels; all 192 v-channels.
__global__ __launch_bounds__(256) void kTv_conv(const ushort_t* __restrict__ qkvb,
                                                const float* __restrict__ wdw,
                                                ushort_t* __restrict__ vT) {
    __shared__ ushort_t kin[192][3][36];
    __shared__ float wl[192 * 9];
    const int tid = threadIdx.x;
    const int y = blockIdx.x >> 3;
    const int x0 = (blockIdx.x & 7) * 32;
    for (int e = tid; e < 1728; e += 256) wl[e] = wdw[3456 + e];
    for (int i = 0; i < 41; i++) {
        int c = tid + i * 256;
        if (c < 10368) {                     // 192ch * 3rows * 18 ushort2
            int ch = c / 54, rem = c % 54;
            int rr = rem / 18, s = rem % 18;
            int yy = y - 1 + rr;
            int gx = x0 - 2 + s * 2;
            ushort_t v0 = 0, v1 = 0;
            if (yy >= 0 && yy <= 255) {
                const ushort_t* src = qkvb + (long)(384 + ch) * NPIX + yy * IW;
                if (gx >= 0 && gx <= 255) v0 = src[gx];
                if (gx + 1 >= 0 && gx + 1 <= 255) v1 = src[gx + 1];
            }
            kin[ch][rr][s * 2] = v0;
            kin[ch][rr][s * 2 + 1] = v1;
        }
    }
    __syncthreads();
    const int p = tid & 31, cg = tid >> 5;
    const long n = (long)y * IW + x0 + p;
    unsigned int packed[12];
    #pragma unroll
    for (int cc2 = 0; cc2 < 12; cc2++) {
        unsigned int pk = 0;
        #pragma unroll
        for (int half = 0; half < 2; half++) {
            int ch = cg * 24 + cc2 * 2 + half;
            float a = 0.f;
            #pragma unroll
            for (int rr = 0; rr < 3; rr++)
                #pragma unroll
                for (int dx = 0; dx < 3; dx++)
                    a += wl[ch * 9 + rr * 3 + dx] * b2f(kin[ch][rr][p + 1 + dx]);
            pk |= ((unsigned int)f2b(a)) << (16 * half);
        }
        packed[cc2] = pk;
    }
    int4* dst = reinterpret_cast<int4*>(vT + n * 200 + cg * 24);
    #pragma unroll
    for (int w = 0; w < 3; w++)
        dst[w] = make_int4(packed[w * 4], packed[w * 4 + 1], packed[w * 4 + 2], packed[w * 4 + 3]);
    if (cg == 7)
        *reinterpret_cast<int4*>(vT + n * 200 + 192) = make_int4(0, 0, 0, 0);
}

// ---------------- K2: Gram partials from materialized bf16 dw(q),dw(k)
__global__ __launch_bounds__(256) void k2_gram(const ushort_t* __restrict__ dwb,
                                               float* __restrict__ Sp,
                                               float* __restrict__ sqq,
                                               float* __restrict__ sqk,
                                               int nchk, int nsub) {
    __shared__ ushort_t qs[48][264];
    __shared__ ushort_t ks[48][264];
    const int tid = threadIdx.x;
    const int chunk = blockIdx.x;
    const int h = blockIdx.y;
    float g[9];
    #pragma unroll
    for (int i = 0; i < 9; i++) g[i] = 0.f;
    float ss = 0.f;
    const int c0 = 3 * (tid >> 4);
    const int d0 = 3 * (tid & 15);

    for (int sub = 0; sub < nsub; sub++) {
        const long p0 = ((long)chunk * nsub + sub) * 256;
        __syncthreads();
        for (int e = tid; e < 96 * 64; e += 256) {
            int cl = e >> 6, p4 = e & 63;
            int chg = (cl < 48) ? (h * 48 + cl) : (192 + h * 48 + (cl - 48));
            ushort4 v = *reinterpret_cast<const ushort4*>(dwb + (long)chg * NPIX + p0 + p4 * 4);
            if (cl < 48) *reinterpret_cast<ushort4*>(&qs[cl][p4 * 4]) = v;
            else         *reinterpret_cast<ushort4*>(&ks[cl - 48][p4 * 4]) = v;
        }
        __syncthreads();
        #pragma unroll 4
        for (int p4 = 0; p4 < 64; p4++) {
            float qa[3][4], ka[3][4];
            #pragma unroll
            for (int i = 0; i < 3; i++) {
                ushort4 v = *reinterpret_cast<const ushort4*>(&qs[c0 + i][p4 * 4]);
                qa[i][0] = b2f(v.x); qa[i][1] = b2f(v.y); qa[i][2] = b2f(v.z); qa[i][3] = b2f(v.w);
            }
            #pragma unroll
            for (int jj = 0; jj < 3; jj++) {
                ushort4 v = *reinterpret_cast<const ushort4*>(&ks[d0 + jj][p4 * 4]);
                ka[jj][0] = b2f(v.x); ka[jj][1] = b2f(v.y); ka[jj][2] = b2f(v.z); ka[jj][3] = b2f(v.w);
            }
            #pragma unroll
            for (int i = 0; i < 3; i++)
                #pragma unroll
                for (int jj = 0; jj < 3; jj++)
                    g[i * 3 + jj] += qa[i][0] * ka[jj][0] + qa[i][1] * ka[jj][1] +
                                     qa[i][2] * ka[jj][2] + qa[i][3] * ka[jj][3];
        }
        if (tid < 96) {
            const ushort_t* row = (tid < 48) ? &qs[tid][0] : &ks[tid - 48][0];
            for (int p = 0; p < 256; p += 4) {
                ushort4 v = *reinterpret_cast<const ushort4*>(row + p);
                float a = b2f(v.x), bq = b2f(v.y), c = b2f(v.z), d = b2f(v.w);
                ss += a * a + bq * bq + c * c + d * d;
            }
        }
    }
    #pragma unroll
    for (int i = 0; i < 3; i++)
        #pragma unroll
        for (int jj = 0; jj < 3; jj++)
            Sp[((long)h * 2304 + (c0 + i) * 48 + (d0 + jj)) * nchk + chunk] = g[i * 3 + jj];
    if (tid < 48) sqq[(h * 48 + tid) * nchk + chunk] = ss;
    else if (tid < 96) sqk[(h * 48 + (tid - 48)) * nchk + chunk] = ss;
}

// ---------------- K3a: wave-per-element reduce
__global__ __launch_bounds__(256) void k3a_reduce(const float* __restrict__ Sp,
                                                  const float* __restrict__ sqq,
                                                  const float* __restrict__ sqk,
                                                  float* __restrict__ S,
                                                  float* __restrict__ sumsq,
                                                  int nchk) {
    const int wid = threadIdx.x >> 6, lane = threadIdx.x & 63;
    const int e = blockIdx.x * 4 + wid;
    const float* p;
    if (e < 9216) {
        p = Sp + (long)e * nchk;
    } else {
        int c = e - 9216;
        if (c >= 384) return;
        p = (c < 192) ? (sqq + (long)c * nchk) : (sqk + (long)(c - 192) * nchk);
    }
    float s = 0.f;
    for (int i = lane; i < nchk; i += 64) s += p[i];
    #pragma unroll
    for (int m = 32; m; m >>= 1) s += __shfl_xor(s, m, 64);
    if (lane == 0) {
        if (e < 9216) S[e] = s;
        else sumsq[e - 9216] = s;
    }
}

// ---------------- K3b: norms, noise MLP, softmax -> attn[4][48][48]
__global__ __launch_bounds__(256) void k3b_attn(const float* __restrict__ S,
                                                const float* __restrict__ sumsq,
                                                const float* __restrict__ noise,
                                                const float* __restrict__ btemp,
                                                const float* __restrict__ w_nm1,
                                                const float* __restrict__ w_nm2,
                                                float* __restrict__ attn, int b) {
    __shared__ float sA[48][49];
    __shared__ float invq[48], invk[48];
    __shared__ float stemp;
    const int h = blockIdx.x, tid = threadIdx.x;
    for (int e = tid; e < 2304; e += 256)
        sA[e / 48][e % 48] = S[h * 2304 + e];
    if (tid < 96) {
        float s = (tid < 48) ? sumsq[h * 48 + tid] : sumsq[192 + h * 48 + (tid - 48)];
        float inv = 1.f / fmaxf(sqrtf(s), 1e-12f);
        if (tid < 48) invq[tid] = inv; else invk[tid - 48] = inv;
    }
    if (tid == 0) {
        float nz = noise[b];
        float a = 0.f;
        for (int i = 0; i < 48; i++) {
            float t = w_nm1[i] * nz;
            t = (t >= 0.f) ? t : 0.2f * t;
            a += w_nm2[h * 48 + i] * t;
        }
        float sig = 1.f / (1.f + expf(-a));
        stemp = btemp[h] * (2.f - sig);
    }
    __syncthreads();
    for (int e = tid; e < 2304; e += 256) {
        int c = e / 48, d = e % 48;
        sA[c][d] *= invq[c] * invk[d] * stemp;
    }
    __syncthreads();
    if (tid < 48) {
        float m = -1e30f;
        for (int d = 0; d < 48; d++) m = fmaxf(m, sA[tid][d]);
        float sum = 0.f;
        for (int d = 0; d < 48; d++) {
            float e_ = expf(sA[tid][d] - m);
            sA[tid][d] = e_;
            sum += e_;
        }
        float r = 1.f / sum;
        for (int d = 0; d < 48; d++)
            attn[h * 2304 + tid * 48 + d] = sA[tid][d] * r;
    }
}

// ---------------- K4: W_eff[o][j] bf16 = sum_c w_out[o][h*48+c] * attn[h][c][d]
__global__ __launch_bounds__(256) void k4_weff(const float* __restrict__ w_out,
                                               const float* __restrict__ attn,
                                               ushort_t* __restrict__ weffb) {
    int e = blockIdx.x * 256 + threadIdx.x;
    int o = e / 192, j = e % 192;
    int h = j / 48, d = j % 48;
    const float* wr = w_out + o * 192 + h * 48;
    const float* ar = attn + h * 2304 + d;
    float s = 0.f;
    #pragma unroll
    for (int c = 0; c < 48; c++) s += wr[c] * ar[c * 48];
    weffb[e] = f2b(s);
}

extern "C" void kernel_launch(void* const* d_in, const int* in_sizes, int n_in,
                              void* d_out, int out_size, void* d_ws, size_t ws_size,
                              hipStream_t stream) {
    const float* x      = (const float*)d_in[0];
    const float* noise  = (const float*)d_in[1];
    const float* btemp  = (const float*)d_in[2];
    const float* w_nm1  = (const float*)d_in[3];
    const float* w_nm2  = (const float*)d_in[4];
    const float* w_qkv  = (const float*)d_in[5];
    const float* w_dw   = (const float*)d_in[6];
    const float* w_out  = (const float*)d_in[7];
    float* out = (float*)d_out;
    float* ws = (float*)d_ws;

    // Workspace plan (float-slot offsets), peak 38,010,880 floats = 152.0 MB:
    //  region A [0, 18874368): qkvb bf16[576][NPIX]  (live: k1..kTv)
    //     aliased afterwards by: Sp(2359296), sqq(49152), sqk(49152), S(9216),
    //                            sumsq(384), attn(9216), weffb(bf16 36864)
    //  region B [18874368, 25427968): xT/vT bf16[65536][200] (xT: kT..k1, vT: kTv..k5b)
    //  region C [25427968, 38010880): dwb bf16[384][NPIX] (kdw..k2)
    ushort_t* qkvb = (ushort_t*)ws;
    float* Sp    = ws;
    float* sqq   = Sp + 9216L * 256;
    float* sqk   = sqq + 49152;
    float* S     = sqk + 49152;
    float* sumsq = S + 9216;
    float* attn  = sumsq + 384;
    ushort_t* weffb = (ushort_t*)(attn + 9216);
    ushort_t* xT  = (ushort_t*)(ws + 18874368);
    ushort_t* vT  = xT;
    ushort_t* dwb = (ushort_t*)(ws + 25427968);

    for (int b = 0; b < 2; b++) {
        const float* xb = x + (long)b * 192 * NPIX;
        float* outb = out + (long)b * 192 * NPIX;
        kT_transpose<<<1024, 256, 0, stream>>>(xb, xT);
        kgemm_mfma<0, 1><<<dim3(9, 512), 256, 0, stream>>>(w_qkv, xT, qkvb);
        kdw_conv<<<dim3(64, 384), 256, 0, stream>>>(qkvb, w_dw, dwb);
        kTv_conv<<<2048, 256, 0, stream>>>(qkvb, w_dw, vT);
        k2_gram<<<dim3(256, 4), 256, 0, stream>>>(dwb, Sp, sqq, sqk, 256, 1);
        k3a_reduce<<<2400, 256, 0, stream>>>(Sp, sqq, sqk, S, sumsq, 256);
        k3b_attn<<<4, 256, 0, stream>>>(S, sumsq, noise, btemp, w_nm1, w_nm2, attn, b);
        k4_weff<<<144, 256, 0, stream>>>(w_out, attn, weffb);
        kgemm_mfma<1, 0><<<dim3(3, 512), 256, 0, stream>>>(weffb, vT, outb);
    }
}

// Round 6
// 481.954 us; speedup vs baseline: 5.2622x; 1.2873x over previous
//
#include <hip/hip_runtime.h>
#include <hip/hip_bf16.h>

#define NPIX 65536
#define IW 256

typedef unsigned short ushort_t;
typedef __attribute__((ext_vector_type(8))) short bf16x8;
typedef __attribute__((ext_vector_type(4))) float f32x4;

__device__ __forceinline__ float b2f(ushort_t u) {
    union { unsigned int i; float f; } v;
    v.i = ((unsigned int)u) << 16;
    return v.f;
}
__device__ __forceinline__ ushort_t f2b(float f) {
    __hip_bfloat16 h = __float2bfloat16(f);
    return *reinterpret_cast<ushort_t*>(&h);
}

// ---------------- KT: xT[n][200] bf16 <- transpose of x fp32 [192][65536]
__global__ __launch_bounds__(256) void kT_transpose(const float* __restrict__ x,
                                                    ushort_t* __restrict__ xT) {
    __shared__ ushort_t Ls[192][66];
    const int tid = threadIdx.x;
    const long n0 = (long)blockIdx.x * 64;
    #pragma unroll
    for (int i = 0; i < 24; i++) {           // 192 rows x 32 float2
        int e = tid + i * 256;
        int k = e >> 5, n2 = e & 31;
        float2 v = *reinterpret_cast<const float2*>(x + (long)k * NPIX + n0 + n2 * 2);
        ushort2 o = make_ushort2(f2b(v.x), f2b(v.y));
        *reinterpret_cast<ushort2*>(&Ls[k][n2 * 2]) = o;
    }
    __syncthreads();
    const int n = tid >> 2, seg = tid & 3;
    const int kb = seg * 48;
    ushort_t* dst = xT + (n0 + n) * 200 + kb;
    #pragma unroll
    for (int w = 0; w < 6; w++) {
        unsigned int p0 = (unsigned int)Ls[kb + w * 8 + 0][n] | ((unsigned int)Ls[kb + w * 8 + 1][n] << 16);
        unsigned int p1 = (unsigned int)Ls[kb + w * 8 + 2][n] | ((unsigned int)Ls[kb + w * 8 + 3][n] << 16);
        unsigned int p2 = (unsigned int)Ls[kb + w * 8 + 4][n] | ((unsigned int)Ls[kb + w * 8 + 5][n] << 16);
        unsigned int p3 = (unsigned int)Ls[kb + w * 8 + 6][n] | ((unsigned int)Ls[kb + w * 8 + 7][n] << 16);
        *reinterpret_cast<int4*>(dst + w * 8) = make_int4(p0, p1, p2, p3);
    }
    if (seg == 3)
        *reinterpret_cast<int4*>(xT + (n0 + n) * 200 + 192) = make_int4(0, 0, 0, 0);
}

// ---------------- KTB: vT[n][200] bf16 <- transpose of bf16 [192][65536]
__global__ __launch_bounds__(256) void kTb_transpose(const ushort_t* __restrict__ src,
                                                     ushort_t* __restrict__ dT) {
    __shared__ ushort_t Ls[192][66];
    const int tid = threadIdx.x;
    const long n0 = (long)blockIdx.x * 64;
    #pragma unroll
    for (int i = 0; i < 24; i++) {           // 192 rows x 32 ushort2
        int e = tid + i * 256;
        int k = e >> 5, n2 = e & 31;
        ushort2 v = *reinterpret_cast<const ushort2*>(src + (long)k * NPIX + n0 + n2 * 2);
        *reinterpret_cast<ushort2*>(&Ls[k][n2 * 2]) = v;
    }
    __syncthreads();
    const int n = tid >> 2, seg = tid & 3;
    const int kb = seg * 48;
    ushort_t* dst = dT + (n0 + n) * 200 + kb;
    #pragma unroll
    for (int w = 0; w < 6; w++) {
        unsigned int p0 = (unsigned int)Ls[kb + w * 8 + 0][n] | ((unsigned int)Ls[kb + w * 8 + 1][n] << 16);
        unsigned int p1 = (unsigned int)Ls[kb + w * 8 + 2][n] | ((unsigned int)Ls[kb + w * 8 + 3][n] << 16);
        unsigned int p2 = (unsigned int)Ls[kb + w * 8 + 4][n] | ((unsigned int)Ls[kb + w * 8 + 5][n] << 16);
        unsigned int p3 = (unsigned int)Ls[kb + w * 8 + 6][n] | ((unsigned int)Ls[kb + w * 8 + 7][n] << 16);
        *reinterpret_cast<int4*>(dst + w * 8) = make_int4(p0, p1, p2, p3);
    }
    if (seg == 3)
        *reinterpret_cast<int4*>(dT + (n0 + n) * 200 + 192) = make_int4(0, 0, 0, 0);
}

// ---------------- KGEMM (MFMA bf16): C[m][n] = sum_k A[m][k] * BT[n][k]
template<int A_BF16, int OUT_BF16>
__global__ __launch_bounds__(256) void kgemm_mfma(const void* __restrict__ Aptr,
                                                  const ushort_t* __restrict__ BT,
                                                  void* __restrict__ Cout) {
    __shared__ ushort_t As[64 * 200];
    __shared__ ushort_t Bs[128 * 200];
    const int tid = threadIdx.x;
    const int lane = tid & 63;
    const int wave = tid >> 6;
    const int m_base = blockIdx.x * 64;
    const long n_base = (long)blockIdx.y * 128;

    #pragma unroll
    for (int i = 0; i < 12; i++) {
        int c = tid + i * 256;
        int m = c / 48, k4 = c % 48;
        if (A_BF16) {
            const ushort_t* A = (const ushort_t*)Aptr;
            ushort4 v = *reinterpret_cast<const ushort4*>(A + (long)(m_base + m) * 192 + k4 * 4);
            *reinterpret_cast<ushort4*>(&As[m * 200 + k4 * 4]) = v;
        } else {
            const float* A = (const float*)Aptr;
            float4 v = *reinterpret_cast<const float4*>(A + (long)(m_base + m) * 192 + k4 * 4);
            ushort4 o = make_ushort4(f2b(v.x), f2b(v.y), f2b(v.z), f2b(v.w));
            *reinterpret_cast<ushort4*>(&As[m * 200 + k4 * 4]) = o;
        }
    }
    {
        const ushort_t* srcbase = BT + n_base * 200;
        #pragma unroll
        for (int i = 0; i < 13; i++) {
            int c = tid + i * 256;
            if (c < 3200) {
                int4 v = *reinterpret_cast<const int4*>(srcbase + c * 8);
                *reinterpret_cast<int4*>(&Bs[c * 8]) = v;
            }
        }
    }
    __syncthreads();

    const int r15 = lane & 15;
    const int g8 = (lane >> 4) * 8;
    const int nw = wave * 32;
    f32x4 acc[4][2];
    #pragma unroll
    for (int mi = 0; mi < 4; mi++)
        #pragma unroll
        for (int ni = 0; ni < 2; ni++)
            acc[mi][ni] = (f32x4){0.f, 0.f, 0.f, 0.f};

    #pragma unroll
    for (int kk = 0; kk < 192; kk += 32) {
        bf16x8 a[4], b[2];
        #pragma unroll
        for (int mi = 0; mi < 4; mi++)
            a[mi] = *reinterpret_cast<const bf16x8*>(&As[(mi * 16 + r15) * 200 + kk + g8]);
        #pragma unroll
        for (int ni = 0; ni < 2; ni++)
            b[ni] = *reinterpret_cast<const bf16x8*>(&Bs[(nw + ni * 16 + r15) * 200 + kk + g8]);
        #pragma unroll
        for (int mi = 0; mi < 4; mi++)
            #pragma unroll
            for (int ni = 0; ni < 2; ni++)
                acc[mi][ni] = __builtin_amdgcn_mfma_f32_16x16x32_bf16(a[mi], b[ni], acc[mi][ni], 0, 0, 0);
    }

    const int gq = (lane >> 4) * 4;
    #pragma unroll
    for (int mi = 0; mi < 4; mi++)
        #pragma unroll
        for (int ni = 0; ni < 2; ni++)
            #pragma unroll
            for (int r = 0; r < 4; r++) {
                long m = m_base + mi * 16 + gq + r;
                long n = n_base + nw + ni * 16 + r15;
                if (OUT_BF16) ((ushort_t*)Cout)[m * NPIX + n] = f2b(acc[mi][ni][r]);
                else          ((float*)Cout)[m * NPIX + n] = acc[mi][ni][r];
            }
}

// ---------------- KDW: dst[j] = dwconv3x3(qkvb[ch_off+j]), bf16 in/out
__global__ __launch_bounds__(256) void kdw_conv(const ushort_t* __restrict__ qkvb,
                                                const float* __restrict__ wdw,
                                                ushort_t* __restrict__ dst,
                                                int ch_off) {
    __shared__ ushort_t rows[6][IW];
    const int tid = threadIdx.x;
    const int j = blockIdx.y;
    const int y0 = blockIdx.x * 4;
    const ushort_t* src = qkvb + (long)(ch_off + j) * NPIX;
    float wv[9];
    #pragma unroll
    for (int t = 0; t < 9; t++) wv[t] = wdw[(ch_off + j) * 9 + t];
    for (int e = tid; e < 6 * 128; e += 256) {
        int r = e >> 7, xh = e & 127;
        int yy = y0 - 1 + r;
        ushort2 val = (yy >= 0 && yy <= 255)
            ? *reinterpret_cast<const ushort2*>(src + yy * IW + xh * 2)
            : make_ushort2(0, 0);
        *reinterpret_cast<ushort2*>(&rows[r][xh * 2]) = val;
    }
    __syncthreads();
    const int x = tid;
    #pragma unroll
    for (int r = 0; r < 4; r++) {
        float a = 0.f;
        #pragma unroll
        for (int dy = 0; dy < 3; dy++) {
            const ushort_t* rw = rows[r + dy];
            if (x > 0)   a += wv[dy * 3 + 0] * b2f(rw[x - 1]);
                         a += wv[dy * 3 + 1] * b2f(rw[x]);
            if (x < 255) a += wv[dy * 3 + 2] * b2f(rw[x + 1]);
        }
        dst[(long)j * NPIX + (y0 + r) * IW + x] = f2b(a);
    }
}

// ---------------- K2: Gram partials from materialized bf16 dw(q),dw(k)
__global__ __launch_bounds__(256) void k2_gram(const ushort_t* __restrict__ dwb,
                                               float* __restrict__ Sp,
                                               float* __restrict__ sqq,
                                               float* __restrict__ sqk,
                                               int nchk, int nsub) {
    __shared__ ushort_t qs[48][264];
    __shared__ ushort_t ks[48][264];
    const int tid = threadIdx.x;
    const int chunk = blockIdx.x;
    const int h = blockIdx.y;
    float g[9];
    #pragma unroll
    for (int i = 0; i < 9; i++) g[i] = 0.f;
    float ss = 0.f;
    const int c0 = 3 * (tid >> 4);
    const int d0 = 3 * (tid & 15);

    for (int sub = 0; sub < nsub; sub++) {
        const long p0 = ((long)chunk * nsub + sub) * 256;
        __syncthreads();
        for (int e = tid; e < 96 * 64; e += 256) {
            int cl = e >> 6, p4 = e & 63;
            int chg = (cl < 48) ? (h * 48 + cl) : (192 + h * 48 + (cl - 48));
            ushort4 v = *reinterpret_cast<const ushort4*>(dwb + (long)chg * NPIX + p0 + p4 * 4);
            if (cl < 48) *reinterpret_cast<ushort4*>(&qs[cl][p4 * 4]) = v;
            else         *reinterpret_cast<ushort4*>(&ks[cl - 48][p4 * 4]) = v;
        }
        __syncthreads();
        #pragma unroll 4
        for (int p4 = 0; p4 < 64; p4++) {
            float qa[3][4], ka[3][4];
            #pragma unroll
            for (int i = 0; i < 3; i++) {
                ushort4 v = *reinterpret_cast<const ushort4*>(&qs[c0 + i][p4 * 4]);
                qa[i][0] = b2f(v.x); qa[i][1] = b2f(v.y); qa[i][2] = b2f(v.z); qa[i][3] = b2f(v.w);
            }
            #pragma unroll
            for (int jj = 0; jj < 3; jj++) {
                ushort4 v = *reinterpret_cast<const ushort4*>(&ks[d0 + jj][p4 * 4]);
                ka[jj][0] = b2f(v.x); ka[jj][1] = b2f(v.y); ka[jj][2] = b2f(v.z); ka[jj][3] = b2f(v.w);
            }
            #pragma unroll
            for (int i = 0; i < 3; i++)
                #pragma unroll
                for (int jj = 0; jj < 3; jj++)
                    g[i * 3 + jj] += qa[i][0] * ka[jj][0] + qa[i][1] * ka[jj][1] +
                                     qa[i][2] * ka[jj][2] + qa[i][3] * ka[jj][3];
        }
        if (tid < 96) {
            const ushort_t* row = (tid < 48) ? &qs[tid][0] : &ks[tid - 48][0];
            for (int p = 0; p < 256; p += 4) {
                ushort4 v = *reinterpret_cast<const ushort4*>(row + p);
                float a = b2f(v.x), bq = b2f(v.y), c = b2f(v.z), d = b2f(v.w);
                ss += a * a + bq * bq + c * c + d * d;
            }
        }
    }
    #pragma unroll
    for (int i = 0; i < 3; i++)
        #pragma unroll
        for (int jj = 0; jj < 3; jj++)
            Sp[((long)h * 2304 + (c0 + i) * 48 + (d0 + jj)) * nchk + chunk] = g[i * 3 + jj];
    if (tid < 48) sqq[(h * 48 + tid) * nchk + chunk] = ss;
    else if (tid < 96) sqk[(h * 48 + (tid - 48)) * nchk + chunk] = ss;
}

// ---------------- K3a: wave-per-element reduce
__global__ __launch_bounds__(256) void k3a_reduce(const float* __restrict__ Sp,
                                                  const float* __restrict__ sqq,
                                                  const float* __restrict__ sqk,
                                                  float* __restrict__ S,
                                                  float* __restrict__ sumsq,
                                                  int nchk) {
    const int wid = threadIdx.x >> 6, lane = threadIdx.x & 63;
    const int e = blockIdx.x * 4 + wid;
    const float* p;
    if (e < 9216) {
        p = Sp + (long)e * nchk;
    } else {
        int c = e - 9216;
        if (c >= 384) return;
        p = (c < 192) ? (sqq + (long)c * nchk) : (sqk + (long)(c - 192) * nchk);
    }
    float s = 0.f;
    for (int i = lane; i < nchk; i += 64) s += p[i];
    #pragma unroll
    for (int m = 32; m; m >>= 1) s += __shfl_xor(s, m, 64);
    if (lane == 0) {
        if (e < 9216) S[e] = s;
        else sumsq[e - 9216] = s;
    }
}

// ---------------- K3b: norms, noise MLP, softmax -> attn[4][48][48]
__global__ __launch_bounds__(256) void k3b_attn(const float* __restrict__ S,
                                                const float* __restrict__ sumsq,
                                                const float* __restrict__ noise,
                                                const float* __restrict__ btemp,
                                                const float* __restrict__ w_nm1,
                                                const float* __restrict__ w_nm2,
                                                float* __restrict__ attn, int b) {
    __shared__ float sA[48][49];
    __shared__ float invq[48], invk[48];
    __shared__ float stemp;
    const int h = blockIdx.x, tid = threadIdx.x;
    for (int e = tid; e < 2304; e += 256)
        sA[e / 48][e % 48] = S[h * 2304 + e];
    if (tid < 96) {
        float s = (tid < 48) ? sumsq[h * 48 + tid] : sumsq[192 + h * 48 + (tid - 48)];
        float inv = 1.f / fmaxf(sqrtf(s), 1e-12f);
        if (tid < 48) invq[tid] = inv; else invk[tid - 48] = inv;
    }
    if (tid == 0) {
        float nz = noise[b];
        float a = 0.f;
        for (int i = 0; i < 48; i++) {
            float t = w_nm1[i] * nz;
            t = (t >= 0.f) ? t : 0.2f * t;
            a += w_nm2[h * 48 + i] * t;
        }
        float sig = 1.f / (1.f + expf(-a));
        stemp = btemp[h] * (2.f - sig);
    }
    __syncthreads();
    for (int e = tid; e < 2304; e += 256) {
        int c = e / 48, d = e % 48;
        sA[c][d] *= invq[c] * invk[d] * stemp;
    }
    __syncthreads();
    if (tid < 48) {
        float m = -1e30f;
        for (int d = 0; d < 48; d++) m = fmaxf(m, sA[tid][d]);
        float sum = 0.f;
        for (int d = 0; d < 48; d++) {
            float e_ = expf(sA[tid][d] - m);
            sA[tid][d] = e_;
            sum += e_;
        }
        float r = 1.f / sum;
        for (int d = 0; d < 48; d++)
            attn[h * 2304 + tid * 48 + d] = sA[tid][d] * r;
    }
}

// ---------------- K4: W_eff[o][j] bf16 = sum_c w_out[o][h*48+c] * attn[h][c][d]
__global__ __launch_bounds__(256) void k4_weff(const float* __restrict__ w_out,
                                               const float* __restrict__ attn,
                                               ushort_t* __restrict__ weffb) {
    int e = blockIdx.x * 256 + threadIdx.x;
    int o = e / 192, j = e % 192;
    int h = j / 48, d = j % 48;
    const float* wr = w_out + o * 192 + h * 48;
    const float* ar = attn + h * 2304 + d;
    float s = 0.f;
    #pragma unroll
    for (int c = 0; c < 48; c++) s += wr[c] * ar[c * 48];
    weffb[e] = f2b(s);
}

extern "C" void kernel_launch(void* const* d_in, const int* in_sizes, int n_in,
                              void* d_out, int out_size, void* d_ws, size_t ws_size,
                              hipStream_t stream) {
    const float* x      = (const float*)d_in[0];
    const float* noise  = (const float*)d_in[1];
    const float* btemp  = (const float*)d_in[2];
    const float* w_nm1  = (const float*)d_in[3];
    const float* w_nm2  = (const float*)d_in[4];
    const float* w_qkv  = (const float*)d_in[5];
    const float* w_dw   = (const float*)d_in[6];
    const float* w_out  = (const float*)d_in[7];
    float* out = (float*)d_out;
    float* ws = (float*)d_ws;

    // Workspace plan (float-slot offsets), peak 38,010,880 floats = 152.0 MB:
    //  region A [0, 18874368): qkvb bf16[576][NPIX]  (live: kgemm..kdw_v)
    //     - dwv bf16[192][NPIX] aliases channels 0..191 (written by kdw_v after
    //       those channels die; live until kTb)
    //     - Sp/sqq/sqk/S/sumsq/attn/weffb alias region A from k2_gram onward
    //  region B [18874368, 25427968): xT (kT..kgemm1) then vT (kTb..kgemm2)
    //  region C [25427968, 38010880): dwb bf16[384][NPIX] (kdw_qk..k2)
    ushort_t* qkvb = (ushort_t*)ws;
    ushort_t* dwv  = (ushort_t*)ws;              // channels 0..191 of qkvb region
    float* Sp    = ws;
    float* sqq   = Sp + 9216L * 256;
    float* sqk   = sqq + 49152;
    float* S     = sqk + 49152;
    float* sumsq = S + 9216;
    float* attn  = sumsq + 384;
    ushort_t* weffb = (ushort_t*)(attn + 9216);
    ushort_t* xT  = (ushort_t*)(ws + 18874368);
    ushort_t* vT  = xT;
    ushort_t* dwb = (ushort_t*)(ws + 25427968);

    for (int b = 0; b < 2; b++) {
        const float* xb = x + (long)b * 192 * NPIX;
        float* outb = out + (long)b * 192 * NPIX;
        kT_transpose<<<1024, 256, 0, stream>>>(xb, xT);
        kgemm_mfma<0, 1><<<dim3(9, 512), 256, 0, stream>>>(w_qkv, xT, qkvb);
        kdw_conv<<<dim3(64, 384), 256, 0, stream>>>(qkvb, w_dw, dwb, 0);    // dw(q,k)
        kdw_conv<<<dim3(64, 192), 256, 0, stream>>>(qkvb, w_dw, dwv, 384);  // dw(v) -> dead q region
        kTb_transpose<<<1024, 256, 0, stream>>>(dwv, vT);                   // xT dead, vT reuses
        k2_gram<<<dim3(256, 4), 256, 0, stream>>>(dwb, Sp, sqq, sqk, 256, 1);
        k3a_reduce<<<2400, 256, 0, stream>>>(Sp, sqq, sqk, S, sumsq, 256);
        k3b_attn<<<4, 256, 0, stream>>>(S, sumsq, noise, btemp, w_nm1, w_nm2, attn, b);
        k4_weff<<<144, 256, 0, stream>>>(w_out, attn, weffb);
        kgemm_mfma<1, 0><<<dim3(3, 512), 256, 0, stream>>>(weffb, vT, outb);
    }
}

// Round 8
// 411.055 us; speedup vs baseline: 6.1698x; 1.1725x over previous
//
#include <hip/hip_runtime.h>
#include <hip/hip_bf16.h>

#define NPIX 65536
#define IW 256

typedef unsigned short ushort_t;
typedef __attribute__((ext_vector_type(8))) short bf16x8;
typedef __attribute__((ext_vector_type(4))) float f32x4;

__device__ __forceinline__ float b2f(ushort_t u) {
    union { unsigned int i; float f; } v;
    v.i = ((unsigned int)u) << 16;
    return v.f;
}
__device__ __forceinline__ ushort_t f2b(float f) {
    __hip_bfloat16 h = __float2bfloat16(f);
    return *reinterpret_cast<ushort_t*>(&h);
}

// ---------------- KT: xT[n][200] bf16 <- transpose of x fp32 [192][65536]
__global__ __launch_bounds__(256) void kT_transpose(const float* __restrict__ x,
                                                    ushort_t* __restrict__ xT) {
    __shared__ ushort_t Ls[192][66];
    const int tid = threadIdx.x;
    const long n0 = (long)blockIdx.x * 64;
    #pragma unroll
    for (int i = 0; i < 24; i++) {
        int e = tid + i * 256;
        int k = e >> 5, n2 = e & 31;
        float2 v = *reinterpret_cast<const float2*>(x + (long)k * NPIX + n0 + n2 * 2);
        ushort2 o = make_ushort2(f2b(v.x), f2b(v.y));
        *reinterpret_cast<ushort2*>(&Ls[k][n2 * 2]) = o;
    }
    __syncthreads();
    const int n = tid >> 2, seg = tid & 3;
    const int kb = seg * 48;
    ushort_t* dst = xT + (n0 + n) * 200 + kb;
    #pragma unroll
    for (int w = 0; w < 6; w++) {
        unsigned int p0 = (unsigned int)Ls[kb + w * 8 + 0][n] | ((unsigned int)Ls[kb + w * 8 + 1][n] << 16);
        unsigned int p1 = (unsigned int)Ls[kb + w * 8 + 2][n] | ((unsigned int)Ls[kb + w * 8 + 3][n] << 16);
        unsigned int p2 = (unsigned int)Ls[kb + w * 8 + 4][n] | ((unsigned int)Ls[kb + w * 8 + 5][n] << 16);
        unsigned int p3 = (unsigned int)Ls[kb + w * 8 + 6][n] | ((unsigned int)Ls[kb + w * 8 + 7][n] << 16);
        *reinterpret_cast<int4*>(dst + w * 8) = make_int4(p0, p1, p2, p3);
    }
    if (seg == 3)
        *reinterpret_cast<int4*>(xT + (n0 + n) * 200 + 192) = make_int4(0, 0, 0, 0);
}

// ---------------- KTB: dT[n][200] bf16 <- transpose of bf16 [192][65536]
__global__ __launch_bounds__(256) void kTb_transpose(const ushort_t* __restrict__ src,
                                                     ushort_t* __restrict__ dT) {
    __shared__ ushort_t Ls[192][66];
    const int tid = threadIdx.x;
    const long n0 = (long)blockIdx.x * 64;
    #pragma unroll
    for (int i = 0; i < 24; i++) {
        int e = tid + i * 256;
        int k = e >> 5, n2 = e & 31;
        ushort2 v = *reinterpret_cast<const ushort2*>(src + (long)k * NPIX + n0 + n2 * 2);
        *reinterpret_cast<ushort2*>(&Ls[k][n2 * 2]) = v;
    }
    __syncthreads();
    const int n = tid >> 2, seg = tid & 3;
    const int kb = seg * 48;
    ushort_t* dst = dT + (n0 + n) * 200 + kb;
    #pragma unroll
    for (int w = 0; w < 6; w++) {
        unsigned int p0 = (unsigned int)Ls[kb + w * 8 + 0][n] | ((unsigned int)Ls[kb + w * 8 + 1][n] << 16);
        unsigned int p1 = (unsigned int)Ls[kb + w * 8 + 2][n] | ((unsigned int)Ls[kb + w * 8 + 3][n] << 16);
        unsigned int p2 = (unsigned int)Ls[kb + w * 8 + 4][n] | ((unsigned int)Ls[kb + w * 8 + 5][n] << 16);
        unsigned int p3 = (unsigned int)Ls[kb + w * 8 + 6][n] | ((unsigned int)Ls[kb + w * 8 + 7][n] << 16);
        *reinterpret_cast<int4*>(dst + w * 8) = make_int4(p0, p1, p2, p3);
    }
    if (seg == 3)
        *reinterpret_cast<int4*>(dT + (n0 + n) * 200 + 192) = make_int4(0, 0, 0, 0);
}

// ---------------- KGEMM (MFMA bf16): C[m][n] = sum_k A[m][k] * BT[n][k]
template<int A_BF16, int OUT_BF16>
__global__ __launch_bounds__(256) void kgemm_mfma(const void* __restrict__ Aptr,
                                                  const ushort_t* __restrict__ BT,
                                                  void* __restrict__ Cout) {
    __shared__ ushort_t As[64 * 200];
    __shared__ ushort_t Bs[128 * 200];
    const int tid = threadIdx.x;
    const int lane = tid & 63;
    const int wave = tid >> 6;
    const int m_base = blockIdx.x * 64;
    const long n_base = (long)blockIdx.y * 128;

    #pragma unroll
    for (int i = 0; i < 12; i++) {
        int c = tid + i * 256;
        int m = c / 48, k4 = c % 48;
        if (A_BF16) {
            const ushort_t* A = (const ushort_t*)Aptr;
            ushort4 v = *reinterpret_cast<const ushort4*>(A + (long)(m_base + m) * 192 + k4 * 4);
            *reinterpret_cast<ushort4*>(&As[m * 200 + k4 * 4]) = v;
        } else {
            const float* A = (const float*)Aptr;
            float4 v = *reinterpret_cast<const float4*>(A + (long)(m_base + m) * 192 + k4 * 4);
            ushort4 o = make_ushort4(f2b(v.x), f2b(v.y), f2b(v.z), f2b(v.w));
            *reinterpret_cast<ushort4*>(&As[m * 200 + k4 * 4]) = o;
        }
    }
    {
        const ushort_t* srcbase = BT + n_base * 200;
        #pragma unroll
        for (int i = 0; i < 13; i++) {
            int c = tid + i * 256;
            if (c < 3200) {
                int4 v = *reinterpret_cast<const int4*>(srcbase + c * 8);
                *reinterpret_cast<int4*>(&Bs[c * 8]) = v;
            }
        }
    }
    __syncthreads();

    const int r15 = lane & 15;
    const int g8 = (lane >> 4) * 8;
    const int nw = wave * 32;
    f32x4 acc[4][2];
    #pragma unroll
    for (int mi = 0; mi < 4; mi++)
        #pragma unroll
        for (int ni = 0; ni < 2; ni++)
            acc[mi][ni] = (f32x4){0.f, 0.f, 0.f, 0.f};

    #pragma unroll
    for (int kk = 0; kk < 192; kk += 32) {
        bf16x8 a[4], b[2];
        #pragma unroll
        for (int mi = 0; mi < 4; mi++)
            a[mi] = *reinterpret_cast<const bf16x8*>(&As[(mi * 16 + r15) * 200 + kk + g8]);
        #pragma unroll
        for (int ni = 0; ni < 2; ni++)
            b[ni] = *reinterpret_cast<const bf16x8*>(&Bs[(nw + ni * 16 + r15) * 200 + kk + g8]);
        #pragma unroll
        for (int mi = 0; mi < 4; mi++)
            #pragma unroll
            for (int ni = 0; ni < 2; ni++)
                acc[mi][ni] = __builtin_amdgcn_mfma_f32_16x16x32_bf16(a[mi], b[ni], acc[mi][ni], 0, 0, 0);
    }

    const int gq = (lane >> 4) * 4;
    #pragma unroll
    for (int mi = 0; mi < 4; mi++)
        #pragma unroll
        for (int ni = 0; ni < 2; ni++)
            #pragma unroll
            for (int r = 0; r < 4; r++) {
                long m = m_base + mi * 16 + gq + r;
                long n = n_base + nw + ni * 16 + r15;
                if (OUT_BF16) ((ushort_t*)Cout)[m * NPIX + n] = f2b(acc[mi][ni][r]);
                else          ((float*)Cout)[m * NPIX + n] = acc[mi][ni][r];
            }
}

// ---------------- KDW: dst[j] = dwconv3x3(qkvb[ch_off+j]), bf16 in/out
__global__ __launch_bounds__(256) void kdw_conv(const ushort_t* __restrict__ qkvb,
                                                const float* __restrict__ wdw,
                                                ushort_t* __restrict__ dst,
                                                int ch_off) {
    __shared__ ushort_t rows[6][IW];
    const int tid = threadIdx.x;
    const int j = blockIdx.y;
    const int y0 = blockIdx.x * 4;
    const ushort_t* src = qkvb + (long)(ch_off + j) * NPIX;
    float wv[9];
    #pragma unroll
    for (int t = 0; t < 9; t++) wv[t] = wdw[(ch_off + j) * 9 + t];
    for (int e = tid; e < 6 * 128; e += 256) {
        int r = e >> 7, xh = e & 127;
        int yy = y0 - 1 + r;
        ushort2 val = (yy >= 0 && yy <= 255)
            ? *reinterpret_cast<const ushort2*>(src + yy * IW + xh * 2)
            : make_ushort2(0, 0);
        *reinterpret_cast<ushort2*>(&rows[r][xh * 2]) = val;
    }
    __syncthreads();
    const int x = tid;
    #pragma unroll
    for (int r = 0; r < 4; r++) {
        float a = 0.f;
        #pragma unroll
        for (int dy = 0; dy < 3; dy++) {
            const ushort_t* rw = rows[r + dy];
            if (x > 0)   a += wv[dy * 3 + 0] * b2f(rw[x - 1]);
                         a += wv[dy * 3 + 1] * b2f(rw[x]);
            if (x < 255) a += wv[dy * 3 + 2] * b2f(rw[x + 1]);
        }
        dst[(long)j * NPIX + (y0 + r) * IW + x] = f2b(a);
    }
}

// ---------------- K2G: MFMA Gram partials, fragments straight from global.
// grid (256 chunks, 4 heads), 4 waves; wave owns 64-px K-slice.
// Spt layout: [cw][9216] where cw = chunk*4+wave, element E = h*2304 + c*48 + d.
// sqp layout: [cw][384] (q ch 0..191, k ch 192..383).
__global__ __launch_bounds__(256) void k2_gram_mfma(const ushort_t* __restrict__ dwb,
                                                    float* __restrict__ Spt,
                                                    float* __restrict__ sqp) {
    const int tid = threadIdx.x;
    const int lane = tid & 63;
    const int wave = tid >> 6;
    const int chunk = blockIdx.x;
    const int h = blockIdx.y;
    const int r15 = lane & 15;
    const int g = lane >> 4;
    const long n0 = (long)chunk * 256 + wave * 64;
    const ushort_t* qb = dwb + (long)(h * 48) * NPIX + n0;
    const ushort_t* kb = dwb + (long)(192 + h * 48) * NPIX + n0;

    f32x4 acc[3][3];
    #pragma unroll
    for (int mi = 0; mi < 3; mi++)
        #pragma unroll
        for (int nj = 0; nj < 3; nj++)
            acc[mi][nj] = (f32x4){0.f, 0.f, 0.f, 0.f};
    float ssq[3] = {0.f, 0.f, 0.f}, ssk[3] = {0.f, 0.f, 0.f};

    #pragma unroll
    for (int ks = 0; ks < 2; ks++) {
        const int off = ks * 32 + g * 8;
        bf16x8 a[3], bfr[3];
        #pragma unroll
        for (int mi = 0; mi < 3; mi++)
            a[mi] = *reinterpret_cast<const bf16x8*>(qb + (long)(mi * 16 + r15) * NPIX + off);
        #pragma unroll
        for (int nj = 0; nj < 3; nj++)
            bfr[nj] = *reinterpret_cast<const bf16x8*>(kb + (long)(nj * 16 + r15) * NPIX + off);
        #pragma unroll
        for (int mi = 0; mi < 3; mi++)
            #pragma unroll
            for (int j = 0; j < 8; j++) {
                float f = b2f((ushort_t)a[mi][j]);
                ssq[mi] += f * f;
            }
        #pragma unroll
        for (int nj = 0; nj < 3; nj++)
            #pragma unroll
            for (int j = 0; j < 8; j++) {
                float f = b2f((ushort_t)bfr[nj][j]);
                ssk[nj] += f * f;
            }
        #pragma unroll
        for (int mi = 0; mi < 3; mi++)
            #pragma unroll
            for (int nj = 0; nj < 3; nj++)
                acc[mi][nj] = __builtin_amdgcn_mfma_f32_16x16x32_bf16(a[mi], bfr[nj], acc[mi][nj], 0, 0, 0);
    }

    const int cw = chunk * 4 + wave;
    float* outb = Spt + (long)cw * 9216 + h * 2304;
    const int gq = g * 4;
    #pragma unroll
    for (int mi = 0; mi < 3; mi++)
        #pragma unroll
        for (int nj = 0; nj < 3; nj++)
            #pragma unroll
            for (int r = 0; r < 4; r++)
                outb[(mi * 16 + gq + r) * 48 + nj * 16 + r15] = acc[mi][nj][r];

    #pragma unroll
    for (int mi = 0; mi < 3; mi++) {
        ssq[mi] += __shfl_xor(ssq[mi], 16, 64);
        ssq[mi] += __shfl_xor(ssq[mi], 32, 64);
        ssk[mi] += __shfl_xor(ssk[mi], 16, 64);
        ssk[mi] += __shfl_xor(ssk[mi], 32, 64);
    }
    if (lane < 16) {
        float* sqb = sqp + (long)cw * 384;
        #pragma unroll
        for (int mi = 0; mi < 3; mi++) {
            sqb[h * 48 + mi * 16 + lane] = ssq[mi];
            sqb[192 + h * 48 + mi * 16 + lane] = ssk[mi];
        }
    }
}

// ---------------- K3A2: coalesced two-stage reduce over cw (1024 slots, 8 segs)
// grid (38, 8): linear work index w covers 9216 S elements + 384 sumsq channels.
__global__ __launch_bounds__(256) void k3a_reduce2(const float* __restrict__ Spt,
                                                   const float* __restrict__ sqp,
                                                   float* __restrict__ S1,
                                                   float* __restrict__ sq1) {
    const int seg = blockIdx.y;
    const int w = blockIdx.x * 256 + threadIdx.x;
    if (w < 9216) {
        const float* p = Spt + (long)seg * 128 * 9216 + w;
        float s = 0.f;
        for (int i = 0; i < 128; i++) s += p[(long)i * 9216];
        S1[seg * 9216 + w] = s;
    } else if (w < 9600) {
        const int c = w - 9216;
        const float* p = sqp + (long)seg * 128 * 384 + c;
        float s = 0.f;
        for (int i = 0; i < 128; i++) s += p[i * 384];
        sq1[seg * 384 + c] = s;
    }
}

// ---------------- K3b: norms, noise MLP, softmax -> attn[4][48][48]
__global__ __launch_bounds__(256) void k3b_attn(const float* __restrict__ S1,
                                                const float* __restrict__ sq1,
                                                const float* __restrict__ noise,
                                                const float* __restrict__ btemp,
                                                const float* __restrict__ w_nm1,
                                                const float* __restrict__ w_nm2,
                                                float* __restrict__ attn, int b) {
    __shared__ float sA[48][49];
    __shared__ float invq[48], invk[48];
    __shared__ float stemp;
    const int h = blockIdx.x, tid = threadIdx.x;
    for (int e = tid; e < 2304; e += 256) {
        float s = 0.f;
        #pragma unroll
        for (int seg = 0; seg < 8; seg++) s += S1[seg * 9216 + h * 2304 + e];
        sA[e / 48][e % 48] = s;
    }
    if (tid < 96) {
        int c = (tid < 48) ? (h * 48 + tid) : (192 + h * 48 + (tid - 48));
        float s = 0.f;
        #pragma unroll
        for (int seg = 0; seg < 8; seg++) s += sq1[seg * 384 + c];
        float inv = 1.f / fmaxf(sqrtf(s), 1e-12f);
        if (tid < 48) invq[tid] = inv; else invk[tid - 48] = inv;
    }
    if (tid == 0) {
        float nz = noise[b];
        float a = 0.f;
        for (int i = 0; i < 48; i++) {
            float t = w_nm1[i] * nz;
            t = (t >= 0.f) ? t : 0.2f * t;
            a += w_nm2[h * 48 + i] * t;
        }
        float sig = 1.f / (1.f + expf(-a));
        stemp = btemp[h] * (2.f - sig);
    }
    __syncthreads();
    for (int e = tid; e < 2304; e += 256) {
        int c = e / 48, d = e % 48;
        sA[c][d] *= invq[c] * invk[d] * stemp;
    }
    __syncthreads();
    if (tid < 48) {
        float m = -1e30f;
        for (int d = 0; d < 48; d++) m = fmaxf(m, sA[tid][d]);
        float sum = 0.f;
        for (int d = 0; d < 48; d++) {
            float e_ = expf(sA[tid][d] - m);
            sA[tid][d] = e_;
            sum += e_;
        }
        float r = 1.f / sum;
        for (int d = 0; d < 48; d++)
            attn[h * 2304 + tid * 48 + d] = sA[tid][d] * r;
    }
}

// ---------------- K4: W_eff[o][j] bf16 = sum_c w_out[o][h*48+c] * attn[h][c][d]
__global__ __launch_bounds__(256) void k4_weff(const float* __restrict__ w_out,
                                               const float* __restrict__ attn,
                                               ushort_t* __restrict__ weffb) {
    int e = blockIdx.x * 256 + threadIdx.x;
    int o = e / 192, j = e % 192;
    int h = j / 48, d = j % 48;
    const float* wr = w_out + o * 192 + h * 48;
    const float* ar = attn + h * 2304 + d;
    float s = 0.f;
    #pragma unroll
    for (int c = 0; c < 48; c++) s += wr[c] * ar[c * 48];
    weffb[e] = f2b(s);
}

extern "C" void kernel_launch(void* const* d_in, const int* in_sizes, int n_in,
                              void* d_out, int out_size, void* d_ws, size_t ws_size,
                              hipStream_t stream) {
    const float* x      = (const float*)d_in[0];
    const float* noise  = (const float*)d_in[1];
    const float* btemp  = (const float*)d_in[2];
    const float* w_nm1  = (const float*)d_in[3];
    const float* w_nm2  = (const float*)d_in[4];
    const float* w_qkv  = (const float*)d_in[5];
    const float* w_dw   = (const float*)d_in[6];
    const float* w_out  = (const float*)d_in[7];
    float* out = (float*)d_out;
    float* ws = (float*)d_ws;

    // Workspace (float-slot offsets), peak 38,010,880 floats = 152.0 MB:
    //  region A [0, 18874368): qkvb bf16[576][NPIX] (live kgemm1..kdw_v)
    //    - dwv bf16[192][NPIX] aliases slots [0, 6291456) (kdw_v..kTb)
    //    - after kTb: Spt[1024][9216], sqp[1024][384], S1[8][9216], sq1[8][384],
    //      attn, weffb  (k2g..kgemm2) — total 9,934,848 slots < 18,874,368
    //  region B [18874368, 25427968): xT (kT..kgemm1) then vT (kTb..kgemm2)
    //  region C [25427968, 38010880): dwb bf16[384][NPIX] (kdw_qk..k2g)
    ushort_t* qkvb = (ushort_t*)ws;
    ushort_t* dwv  = (ushort_t*)ws;
    float* Spt  = ws;                      // 9,437,184
    float* sqp  = ws + 9437184;            // 393,216
    float* S1   = ws + 9830400;            // 73,728
    float* sq1  = ws + 9904128;            // 3,072
    float* attn = ws + 9907200;            // 9,216
    ushort_t* weffb = (ushort_t*)(ws + 9916416);
    ushort_t* xT  = (ushort_t*)(ws + 18874368);
    ushort_t* vT  = xT;
    ushort_t* dwb = (ushort_t*)(ws + 25427968);

    for (int b = 0; b < 2; b++) {
        const float* xb = x + (long)b * 192 * NPIX;
        float* outb = out + (long)b * 192 * NPIX;
        kT_transpose<<<1024, 256, 0, stream>>>(xb, xT);
        kgemm_mfma<0, 1><<<dim3(9, 512), 256, 0, stream>>>(w_qkv, xT, qkvb);
        kdw_conv<<<dim3(64, 384), 256, 0, stream>>>(qkvb, w_dw, dwb, 0);    // dw(q,k)
        kdw_conv<<<dim3(64, 192), 256, 0, stream>>>(qkvb, w_dw, dwv, 384);  // dw(v)
        kTb_transpose<<<1024, 256, 0, stream>>>(dwv, vT);
        k2_gram_mfma<<<dim3(256, 4), 256, 0, stream>>>(dwb, Spt, sqp);
        k3a_reduce2<<<dim3(38, 8), 256, 0, stream>>>(Spt, sqp, S1, sq1);
        k3b_attn<<<4, 256, 0, stream>>>(S1, sq1, noise, btemp, w_nm1, w_nm2, attn, b);
        k4_weff<<<144, 256, 0, stream>>>(w_out, attn, weffb);
        kgemm_mfma<1, 0><<<dim3(3, 512), 256, 0, stream>>>(weffb, vT, outb);
    }
}

// Round 9
// 332.453 us; speedup vs baseline: 7.6285x; 1.2364x over previous
//
#include <hip/hip_runtime.h>
#include <hip/hip_bf16.h>

#define NPIX 65536
#define IW 256

typedef unsigned short ushort_t;
typedef __attribute__((ext_vector_type(8))) short bf16x8;
typedef __attribute__((ext_vector_type(4))) float f32x4;

__device__ __forceinline__ float b2f(ushort_t u) {
    union { unsigned int i; float f; } v;
    v.i = ((unsigned int)u) << 16;
    return v.f;
}
__device__ __forceinline__ ushort_t f2b(float f) {
    __hip_bfloat16 h = __float2bfloat16(f);
    return *reinterpret_cast<ushort_t*>(&h);
}

// ---------------- KT: xT[n][200] bf16 <- transpose of x fp32 [192][65536]
__global__ __launch_bounds__(256) void kT_transpose(const float* __restrict__ x,
                                                    ushort_t* __restrict__ xT) {
    __shared__ ushort_t Ls[192][66];
    const int tid = threadIdx.x;
    const long n0 = (long)blockIdx.x * 64;
    #pragma unroll
    for (int i = 0; i < 24; i++) {
        int e = tid + i * 256;
        int k = e >> 5, n2 = e & 31;
        float2 v = *reinterpret_cast<const float2*>(x + (long)k * NPIX + n0 + n2 * 2);
        ushort2 o = make_ushort2(f2b(v.x), f2b(v.y));
        *reinterpret_cast<ushort2*>(&Ls[k][n2 * 2]) = o;
    }
    __syncthreads();
    const int n = tid >> 2, seg = tid & 3;
    const int kb = seg * 48;
    ushort_t* dst = xT + (n0 + n) * 200 + kb;
    #pragma unroll
    for (int w = 0; w < 6; w++) {
        unsigned int p0 = (unsigned int)Ls[kb + w * 8 + 0][n] | ((unsigned int)Ls[kb + w * 8 + 1][n] << 16);
        unsigned int p1 = (unsigned int)Ls[kb + w * 8 + 2][n] | ((unsigned int)Ls[kb + w * 8 + 3][n] << 16);
        unsigned int p2 = (unsigned int)Ls[kb + w * 8 + 4][n] | ((unsigned int)Ls[kb + w * 8 + 5][n] << 16);
        unsigned int p3 = (unsigned int)Ls[kb + w * 8 + 6][n] | ((unsigned int)Ls[kb + w * 8 + 7][n] << 16);
        *reinterpret_cast<int4*>(dst + w * 8) = make_int4(p0, p1, p2, p3);
    }
    if (seg == 3)
        *reinterpret_cast<int4*>(xT + (n0 + n) * 200 + 192) = make_int4(0, 0, 0, 0);
}

// ---------------- KTB: dT[n][200] bf16 <- transpose of bf16 [192][65536]
__global__ __launch_bounds__(256) void kTb_transpose(const ushort_t* __restrict__ src,
                                                     ushort_t* __restrict__ dT) {
    __shared__ ushort_t Ls[192][66];
    const int tid = threadIdx.x;
    const long n0 = (long)blockIdx.x * 64;
    #pragma unroll
    for (int i = 0; i < 24; i++) {
        int e = tid + i * 256;
        int k = e >> 5, n2 = e & 31;
        ushort2 v = *reinterpret_cast<const ushort2*>(src + (long)k * NPIX + n0 + n2 * 2);
        *reinterpret_cast<ushort2*>(&Ls[k][n2 * 2]) = v;
    }
    __syncthreads();
    const int n = tid >> 2, seg = tid & 3;
    const int kb = seg * 48;
    ushort_t* dst = dT + (n0 + n) * 200 + kb;
    #pragma unroll
    for (int w = 0; w < 6; w++) {
        unsigned int p0 = (unsigned int)Ls[kb + w * 8 + 0][n] | ((unsigned int)Ls[kb + w * 8 + 1][n] << 16);
        unsigned int p1 = (unsigned int)Ls[kb + w * 8 + 2][n] | ((unsigned int)Ls[kb + w * 8 + 3][n] << 16);
        unsigned int p2 = (unsigned int)Ls[kb + w * 8 + 4][n] | ((unsigned int)Ls[kb + w * 8 + 5][n] << 16);
        unsigned int p3 = (unsigned int)Ls[kb + w * 8 + 6][n] | ((unsigned int)Ls[kb + w * 8 + 7][n] << 16);
        *reinterpret_cast<int4*>(dst + w * 8) = make_int4(p0, p1, p2, p3);
    }
    if (seg == 3)
        *reinterpret_cast<int4*>(dT + (n0 + n) * 200 + 192) = make_int4(0, 0, 0, 0);
}

// ---------------- KGEMM (B-stationary, MFMA bf16): C[m][n] = sum_k A[m][k]*BT[n][k]
// grid = 512 n-tiles; block stages Bs ONCE, loops mtiles A-tiles of 64 rows.
// B read exactly once from HBM; A (<=442 KB) stays L2/L3-resident.
template<int A_BF16, int OUT_BF16>
__global__ __launch_bounds__(256) void kgemm_bstat(const void* __restrict__ Aptr,
                                                   const ushort_t* __restrict__ BT,
                                                   void* __restrict__ Cout,
                                                   int mtiles) {
    __shared__ ushort_t Bs[128 * 200];
    __shared__ ushort_t As[64 * 200];
    const int tid = threadIdx.x;
    const int lane = tid & 63;
    const int wave = tid >> 6;
    const long n_base = (long)blockIdx.x * 128;

    {   // stage B tile once: 128 rows x 400B contiguous
        const ushort_t* srcbase = BT + n_base * 200;
        #pragma unroll
        for (int i = 0; i < 13; i++) {
            int c = tid + i * 256;
            if (c < 3200) {
                int4 v = *reinterpret_cast<const int4*>(srcbase + c * 8);
                *reinterpret_cast<int4*>(&Bs[c * 8]) = v;
            }
        }
    }

    const int r15 = lane & 15;
    const int g8 = (lane >> 4) * 8;
    const int gq = (lane >> 4) * 4;
    const int nw = wave * 32;

    for (int mt = 0; mt < mtiles; mt++) {
        const int m_base = mt * 64;
        __syncthreads();  // prev compute done reading As (and Bs ready on iter 0)
        #pragma unroll
        for (int i = 0; i < 12; i++) {   // 64 x 48 ushort4 chunks = 3072
            int c = tid + i * 256;
            int m = c / 48, k4 = c % 48;
            if (A_BF16) {
                const ushort_t* A = (const ushort_t*)Aptr;
                ushort4 v = *reinterpret_cast<const ushort4*>(A + (long)(m_base + m) * 192 + k4 * 4);
                *reinterpret_cast<ushort4*>(&As[m * 200 + k4 * 4]) = v;
            } else {
                const float* A = (const float*)Aptr;
                float4 v = *reinterpret_cast<const float4*>(A + (long)(m_base + m) * 192 + k4 * 4);
                ushort4 o = make_ushort4(f2b(v.x), f2b(v.y), f2b(v.z), f2b(v.w));
                *reinterpret_cast<ushort4*>(&As[m * 200 + k4 * 4]) = o;
            }
        }
        __syncthreads();

        f32x4 acc[4][2];
        #pragma unroll
        for (int mi = 0; mi < 4; mi++)
            #pragma unroll
            for (int ni = 0; ni < 2; ni++)
                acc[mi][ni] = (f32x4){0.f, 0.f, 0.f, 0.f};

        #pragma unroll
        for (int kk = 0; kk < 192; kk += 32) {
            bf16x8 a[4], b[2];
            #pragma unroll
            for (int mi = 0; mi < 4; mi++)
                a[mi] = *reinterpret_cast<const bf16x8*>(&As[(mi * 16 + r15) * 200 + kk + g8]);
            #pragma unroll
            for (int ni = 0; ni < 2; ni++)
                b[ni] = *reinterpret_cast<const bf16x8*>(&Bs[(nw + ni * 16 + r15) * 200 + kk + g8]);
            #pragma unroll
            for (int mi = 0; mi < 4; mi++)
                #pragma unroll
                for (int ni = 0; ni < 2; ni++)
                    acc[mi][ni] = __builtin_amdgcn_mfma_f32_16x16x32_bf16(a[mi], b[ni], acc[mi][ni], 0, 0, 0);
        }

        #pragma unroll
        for (int mi = 0; mi < 4; mi++)
            #pragma unroll
            for (int ni = 0; ni < 2; ni++)
                #pragma unroll
                for (int r = 0; r < 4; r++) {
                    long m = m_base + mi * 16 + gq + r;
                    long n = n_base + nw + ni * 16 + r15;
                    if (OUT_BF16) ((ushort_t*)Cout)[m * NPIX + n] = f2b(acc[mi][ni][r]);
                    else          ((float*)Cout)[m * NPIX + n] = acc[mi][ni][r];
                }
    }
}

// ---------------- KDW: dst[j] = dwconv3x3(qkvb[ch_off+j]), bf16 in/out
__global__ __launch_bounds__(256) void kdw_conv(const ushort_t* __restrict__ qkvb,
                                                const float* __restrict__ wdw,
                                                ushort_t* __restrict__ dst,
                                                int ch_off) {
    __shared__ ushort_t rows[6][IW];
    const int tid = threadIdx.x;
    const int j = blockIdx.y;
    const int y0 = blockIdx.x * 4;
    const ushort_t* src = qkvb + (long)(ch_off + j) * NPIX;
    float wv[9];
    #pragma unroll
    for (int t = 0; t < 9; t++) wv[t] = wdw[(ch_off + j) * 9 + t];
    for (int e = tid; e < 6 * 128; e += 256) {
        int r = e >> 7, xh = e & 127;
        int yy = y0 - 1 + r;
        ushort2 val = (yy >= 0 && yy <= 255)
            ? *reinterpret_cast<const ushort2*>(src + yy * IW + xh * 2)
            : make_ushort2(0, 0);
        *reinterpret_cast<ushort2*>(&rows[r][xh * 2]) = val;
    }
    __syncthreads();
    const int x = tid;
    #pragma unroll
    for (int r = 0; r < 4; r++) {
        float a = 0.f;
        #pragma unroll
        for (int dy = 0; dy < 3; dy++) {
            const ushort_t* rw = rows[r + dy];
            if (x > 0)   a += wv[dy * 3 + 0] * b2f(rw[x - 1]);
                         a += wv[dy * 3 + 1] * b2f(rw[x]);
            if (x < 255) a += wv[dy * 3 + 2] * b2f(rw[x + 1]);
        }
        dst[(long)j * NPIX + (y0 + r) * IW + x] = f2b(a);
    }
}

// ---------------- K2G: MFMA Gram partials, fragments straight from global.
// grid (64 chunks, 4 heads), 4 waves; wave owns 256-px K-slice (8 MFMA K-steps).
// Spt layout: [cw][9216], cw = chunk*4+wave (256 total); sqp: [cw][384].
__global__ __launch_bounds__(256) void k2_gram_mfma(const ushort_t* __restrict__ dwb,
                                                    float* __restrict__ Spt,
                                                    float* __restrict__ sqp) {
    const int tid = threadIdx.x;
    const int lane = tid & 63;
    const int wave = tid >> 6;
    const int chunk = blockIdx.x;
    const int h = blockIdx.y;
    const int r15 = lane & 15;
    const int g = lane >> 4;
    const long n0 = (long)chunk * 1024 + wave * 256;
    const ushort_t* qb = dwb + (long)(h * 48) * NPIX + n0;
    const ushort_t* kb = dwb + (long)(192 + h * 48) * NPIX + n0;

    f32x4 acc[3][3];
    #pragma unroll
    for (int mi = 0; mi < 3; mi++)
        #pragma unroll
        for (int nj = 0; nj < 3; nj++)
            acc[mi][nj] = (f32x4){0.f, 0.f, 0.f, 0.f};
    float ssq[3] = {0.f, 0.f, 0.f}, ssk[3] = {0.f, 0.f, 0.f};

    for (int ks = 0; ks < 8; ks++) {
        const int off = ks * 32 + g * 8;
        bf16x8 a[3], bfr[3];
        #pragma unroll
        for (int mi = 0; mi < 3; mi++)
            a[mi] = *reinterpret_cast<const bf16x8*>(qb + (long)(mi * 16 + r15) * NPIX + off);
        #pragma unroll
        for (int nj = 0; nj < 3; nj++)
            bfr[nj] = *reinterpret_cast<const bf16x8*>(kb + (long)(nj * 16 + r15) * NPIX + off);
        #pragma unroll
        for (int mi = 0; mi < 3; mi++)
            #pragma unroll
            for (int j = 0; j < 8; j++) {
                float f = b2f((ushort_t)a[mi][j]);
                ssq[mi] += f * f;
            }
        #pragma unroll
        for (int nj = 0; nj < 3; nj++)
            #pragma unroll
            for (int j = 0; j < 8; j++) {
                float f = b2f((ushort_t)bfr[nj][j]);
                ssk[nj] += f * f;
            }
        #pragma unroll
        for (int mi = 0; mi < 3; mi++)
            #pragma unroll
            for (int nj = 0; nj < 3; nj++)
                acc[mi][nj] = __builtin_amdgcn_mfma_f32_16x16x32_bf16(a[mi], bfr[nj], acc[mi][nj], 0, 0, 0);
    }

    const int cw = chunk * 4 + wave;
    float* outb = Spt + (long)cw * 9216 + h * 2304;
    const int gq = g * 4;
    #pragma unroll
    for (int mi = 0; mi < 3; mi++)
        #pragma unroll
        for (int nj = 0; nj < 3; nj++)
            #pragma unroll
            for (int r = 0; r < 4; r++)
                outb[(mi * 16 + gq + r) * 48 + nj * 16 + r15] = acc[mi][nj][r];

    #pragma unroll
    for (int mi = 0; mi < 3; mi++) {
        ssq[mi] += __shfl_xor(ssq[mi], 16, 64);
        ssq[mi] += __shfl_xor(ssq[mi], 32, 64);
        ssk[mi] += __shfl_xor(ssk[mi], 16, 64);
        ssk[mi] += __shfl_xor(ssk[mi], 32, 64);
    }
    if (lane < 16) {
        float* sqb = sqp + (long)cw * 384;
        #pragma unroll
        for (int mi = 0; mi < 3; mi++) {
            sqb[h * 48 + mi * 16 + lane] = ssq[mi];
            sqb[192 + h * 48 + mi * 16 + lane] = ssk[mi];
        }
    }
}

// ---------------- K3A2: coalesced two-stage reduce over cw (256 slots, 8 segs of 32)
__global__ __launch_bounds__(256) void k3a_reduce2(const float* __restrict__ Spt,
                                                   const float* __restrict__ sqp,
                                                   float* __restrict__ S1,
                                                   float* __restrict__ sq1) {
    const int seg = blockIdx.y;
    const int w = blockIdx.x * 256 + threadIdx.x;
    if (w < 9216) {
        const float* p = Spt + (long)seg * 32 * 9216 + w;
        float s = 0.f;
        for (int i = 0; i < 32; i++) s += p[(long)i * 9216];
        S1[seg * 9216 + w] = s;
    } else if (w < 9600) {
        const int c = w - 9216;
        const float* p = sqp + (long)seg * 32 * 384 + c;
        float s = 0.f;
        for (int i = 0; i < 32; i++) s += p[i * 384];
        sq1[seg * 384 + c] = s;
    }
}

// ---------------- K3b: norms, noise MLP, softmax -> attn[4][48][48]
__global__ __launch_bounds__(256) void k3b_attn(const float* __restrict__ S1,
                                                const float* __restrict__ sq1,
                                                const float* __restrict__ noise,
                                                const float* __restrict__ btemp,
                                                const float* __restrict__ w_nm1,
                                                const float* __restrict__ w_nm2,
                                                float* __restrict__ attn, int b) {
    __shared__ float sA[48][49];
    __shared__ float invq[48], invk[48];
    __shared__ float stemp;
    const int h = blockIdx.x, tid = threadIdx.x;
    for (int e = tid; e < 2304; e += 256) {
        float s = 0.f;
        #pragma unroll
        for (int seg = 0; seg < 8; seg++) s += S1[seg * 9216 + h * 2304 + e];
        sA[e / 48][e % 48] = s;
    }
    if (tid < 96) {
        int c = (tid < 48) ? (h * 48 + tid) : (192 + h * 48 + (tid - 48));
        float s = 0.f;
        #pragma unroll
        for (int seg = 0; seg < 8; seg++) s += sq1[seg * 384 + c];
        float inv = 1.f / fmaxf(sqrtf(s), 1e-12f);
        if (tid < 48) invq[tid] = inv; else invk[tid - 48] = inv;
    }
    if (tid == 0) {
        float nz = noise[b];
        float a = 0.f;
        for (int i = 0; i < 48; i++) {
            float t = w_nm1[i] * nz;
            t = (t >= 0.f) ? t : 0.2f * t;
            a += w_nm2[h * 48 + i] * t;
        }
        float sig = 1.f / (1.f + expf(-a));
        stemp = btemp[h] * (2.f - sig);
    }
    __syncthreads();
    for (int e = tid; e < 2304; e += 256) {
        int c = e / 48, d = e % 48;
        sA[c][d] *= invq[c] * invk[d] * stemp;
    }
    __syncthreads();
    if (tid < 48) {
        float m = -1e30f;
        for (int d = 0; d < 48; d++) m = fmaxf(m, sA[tid][d]);
        float sum = 0.f;
        for (int d = 0; d < 48; d++) {
            float e_ = expf(sA[tid][d] - m);
            sA[tid][d] = e_;
            sum += e_;
        }
        float r = 1.f / sum;
        for (int d = 0; d < 48; d++)
            attn[h * 2304 + tid * 48 + d] = sA[tid][d] * r;
    }
}

// ---------------- K4: W_eff[o][j] bf16 = sum_c w_out[o][h*48+c] * attn[h][c][d]
__global__ __launch_bounds__(256) void k4_weff(const float* __restrict__ w_out,
                                               const float* __restrict__ attn,
                                               ushort_t* __restrict__ weffb) {
    int e = blockIdx.x * 256 + threadIdx.x;
    int o = e / 192, j = e % 192;
    int h = j / 48, d = j % 48;
    const float* wr = w_out + o * 192 + h * 48;
    const float* ar = attn + h * 2304 + d;
    float s = 0.f;
    #pragma unroll
    for (int c = 0; c < 48; c++) s += wr[c] * ar[c * 48];
    weffb[e] = f2b(s);
}

extern "C" void kernel_launch(void* const* d_in, const int* in_sizes, int n_in,
                              void* d_out, int out_size, void* d_ws, size_t ws_size,
                              hipStream_t stream) {
    const float* x      = (const float*)d_in[0];
    const float* noise  = (const float*)d_in[1];
    const float* btemp  = (const float*)d_in[2];
    const float* w_nm1  = (const float*)d_in[3];
    const float* w_nm2  = (const float*)d_in[4];
    const float* w_qkv  = (const float*)d_in[5];
    const float* w_dw   = (const float*)d_in[6];
    const float* w_out  = (const float*)d_in[7];
    float* out = (float*)d_out;
    float* ws = (float*)d_ws;

    // Workspace (float-slot offsets), peak 38,010,880 floats = 152.0 MB:
    //  region A [0, 18874368): qkvb bf16[576][NPIX] (live kgemm1..kdw_v)
    //    - dwv bf16[192][NPIX] aliases slots [0, 6291456) (kdw_v..kTb)
    //    - after kTb: Spt[256][9216], sqp[256][384], S1[8][9216], sq1[8][384],
    //      attn, weffb (k2g..kgemm2) — all within dead qkvb/dwv region
    //  region B [18874368, 25427968): xT (kT..kgemm1) then vT (kTb..kgemm2)
    //  region C [25427968, 38010880): dwb bf16[384][NPIX] (kdw_qk..k2g)
    ushort_t* qkvb = (ushort_t*)ws;
    ushort_t* dwv  = (ushort_t*)ws;
    float* Spt  = ws;                      // 2,359,296
    float* sqp  = ws + 9437184;            // 98,304
    float* S1   = ws + 9830400;            // 73,728
    float* sq1  = ws + 9904128;            // 3,072
    float* attn = ws + 9907200;            // 9,216
    ushort_t* weffb = (ushort_t*)(ws + 9916416);
    ushort_t* xT  = (ushort_t*)(ws + 18874368);
    ushort_t* vT  = xT;
    ushort_t* dwb = (ushort_t*)(ws + 25427968);

    for (int b = 0; b < 2; b++) {
        const float* xb = x + (long)b * 192 * NPIX;
        float* outb = out + (long)b * 192 * NPIX;
        kT_transpose<<<1024, 256, 0, stream>>>(xb, xT);
        kgemm_bstat<0, 1><<<512, 256, 0, stream>>>(w_qkv, xT, qkvb, 9);
        kdw_conv<<<dim3(64, 384), 256, 0, stream>>>(qkvb, w_dw, dwb, 0);    // dw(q,k)
        kdw_conv<<<dim3(64, 192), 256, 0, stream>>>(qkvb, w_dw, dwv, 384);  // dw(v)
        kTb_transpose<<<1024, 256, 0, stream>>>(dwv, vT);
        k2_gram_mfma<<<dim3(64, 4), 256, 0, stream>>>(dwb, Spt, sqp);
        k3a_reduce2<<<dim3(38, 8), 256, 0, stream>>>(Spt, sqp, S1, sq1);
        k3b_attn<<<4, 256, 0, stream>>>(S1, sq1, noise, btemp, w_nm1, w_nm2, attn, b);
        k4_weff<<<144, 256, 0, stream>>>(w_out, attn, weffb);
        kgemm_bstat<1, 0><<<512, 256, 0, stream>>>(weffb, vT, outb, 3);
    }
}

// Round 10
// 277.690 us; speedup vs baseline: 9.1329x; 1.1972x over previous
//
#include <hip/hip_runtime.h>
#include <hip/hip_bf16.h>

#define NPIX 65536
#define IW 256

typedef unsigned short ushort_t;
typedef __attribute__((ext_vector_type(8))) short bf16x8;
typedef __attribute__((ext_vector_type(4))) float f32x4;

__device__ __forceinline__ float b2f(ushort_t u) {
    union { unsigned int i; float f; } v;
    v.i = ((unsigned int)u) << 16;
    return v.f;
}
__device__ __forceinline__ ushort_t f2b(float f) {
    __hip_bfloat16 h = __float2bfloat16(f);
    return *reinterpret_cast<ushort_t*>(&h);
}

// ---------------- KGEMM (B-stationary, fused transpose staging, MFMA bf16)
// C[m][n] = sum_k A[m][k] * B[k][n];  B source is row-major [192][NPIX]
// (fp32 if B_F32 else bf16). grid = 512 n-tiles of 128. Per block: B tile is
// transposed INTO LDS Bs[128][200] via a [192][66] scratch tile (Lu) that
// reuses As's LDS slot; then loop over mtiles A-tiles of 64 rows.
template<int B_F32, int A_BF16, int OUT_BF16>
__global__ __launch_bounds__(256) void kgemm_fused(const void* __restrict__ Aptr,
                                                   const void* __restrict__ Bsrc,
                                                   void* __restrict__ Cout,
                                                   int mtiles) {
    __shared__ ushort_t Bs[128 * 200];
    __shared__ ushort_t AsLu[64 * 200];   // Lu[192][66] during B-stage; As after
    const int tid = threadIdx.x;
    const int lane = tid & 63;
    const int wave = tid >> 6;
    const long n_base = (long)blockIdx.x * 128;

    // ---- B-stage with in-LDS transpose: two 64-px halves
    ushort_t (*Lu)[66] = reinterpret_cast<ushort_t (*)[66]>(AsLu);
    #pragma unroll
    for (int half = 0; half < 2; half++) {
        const long n0 = n_base + half * 64;
        __syncthreads();  // Lu reuse between halves
        #pragma unroll
        for (int i = 0; i < 24; i++) {     // 192 rows x 32 elem-pairs
            int e = tid + i * 256;
            int k = e >> 5, n2 = e & 31;
            ushort2 o;
            if (B_F32) {
                float2 v = *reinterpret_cast<const float2*>(
                    (const float*)Bsrc + (long)k * NPIX + n0 + n2 * 2);
                o = make_ushort2(f2b(v.x), f2b(v.y));
            } else {
                o = *reinterpret_cast<const ushort2*>(
                    (const ushort_t*)Bsrc + (long)k * NPIX + n0 + n2 * 2);
            }
            *reinterpret_cast<ushort2*>(&Lu[k][n2 * 2]) = o;
        }
        __syncthreads();
        const int n = tid >> 2, seg = tid & 3;
        const int kb = seg * 48;
        ushort_t* dst = &Bs[(half * 64 + n) * 200 + kb];
        #pragma unroll
        for (int w = 0; w < 6; w++) {
            unsigned int p0 = (unsigned int)Lu[kb + w * 8 + 0][n] | ((unsigned int)Lu[kb + w * 8 + 1][n] << 16);
            unsigned int p1 = (unsigned int)Lu[kb + w * 8 + 2][n] | ((unsigned int)Lu[kb + w * 8 + 3][n] << 16);
            unsigned int p2 = (unsigned int)Lu[kb + w * 8 + 4][n] | ((unsigned int)Lu[kb + w * 8 + 5][n] << 16);
            unsigned int p3 = (unsigned int)Lu[kb + w * 8 + 6][n] | ((unsigned int)Lu[kb + w * 8 + 7][n] << 16);
            *reinterpret_cast<int4*>(dst + w * 8) = make_int4(p0, p1, p2, p3);
        }
    }

    const int r15 = lane & 15;
    const int g8 = (lane >> 4) * 8;
    const int gq = (lane >> 4) * 4;
    const int nw = wave * 32;

    // ---- m-tile loop; AsLu now holds the A tile
    for (int mt = 0; mt < mtiles; mt++) {
        const int m_base = mt * 64;
        __syncthreads();  // prev MFMA reads of As done; pack-phase Lu reads done (iter 0)
        #pragma unroll
        for (int i = 0; i < 12; i++) {     // 64 x 48 ushort4 chunks
            int c = tid + i * 256;
            int m = c / 48, k4 = c % 48;
            if (A_BF16) {
                const ushort_t* A = (const ushort_t*)Aptr;
                ushort4 v = *reinterpret_cast<const ushort4*>(A + (long)(m_base + m) * 192 + k4 * 4);
                *reinterpret_cast<ushort4*>(&AsLu[m * 200 + k4 * 4]) = v;
            } else {
                const float* A = (const float*)Aptr;
                float4 v = *reinterpret_cast<const float4*>(A + (long)(m_base + m) * 192 + k4 * 4);
                ushort4 o = make_ushort4(f2b(v.x), f2b(v.y), f2b(v.z), f2b(v.w));
                *reinterpret_cast<ushort4*>(&AsLu[m * 200 + k4 * 4]) = o;
            }
        }
        __syncthreads();

        f32x4 acc[4][2];
        #pragma unroll
        for (int mi = 0; mi < 4; mi++)
            #pragma unroll
            for (int ni = 0; ni < 2; ni++)
                acc[mi][ni] = (f32x4){0.f, 0.f, 0.f, 0.f};

        #pragma unroll
        for (int kk = 0; kk < 192; kk += 32) {
            bf16x8 a[4], b[2];
            #pragma unroll
            for (int mi = 0; mi < 4; mi++)
                a[mi] = *reinterpret_cast<const bf16x8*>(&AsLu[(mi * 16 + r15) * 200 + kk + g8]);
            #pragma unroll
            for (int ni = 0; ni < 2; ni++)
                b[ni] = *reinterpret_cast<const bf16x8*>(&Bs[(nw + ni * 16 + r15) * 200 + kk + g8]);
            #pragma unroll
            for (int mi = 0; mi < 4; mi++)
                #pragma unroll
                for (int ni = 0; ni < 2; ni++)
                    acc[mi][ni] = __builtin_amdgcn_mfma_f32_16x16x32_bf16(a[mi], b[ni], acc[mi][ni], 0, 0, 0);
        }

        #pragma unroll
        for (int mi = 0; mi < 4; mi++)
            #pragma unroll
            for (int ni = 0; ni < 2; ni++)
                #pragma unroll
                for (int r = 0; r < 4; r++) {
                    long m = m_base + mi * 16 + gq + r;
                    long n = n_base + nw + ni * 16 + r15;
                    if (OUT_BF16) ((ushort_t*)Cout)[m * NPIX + n] = f2b(acc[mi][ni][r]);
                    else          ((float*)Cout)[m * NPIX + n] = acc[mi][ni][r];
                }
    }
}

// ---------------- KDW: all 576 channels; j<384 -> dwb[j], else dwv[j-384]
__global__ __launch_bounds__(256) void kdw_conv(const ushort_t* __restrict__ qkvb,
                                                const float* __restrict__ wdw,
                                                ushort_t* __restrict__ dwb,
                                                ushort_t* __restrict__ dwv) {
    __shared__ ushort_t rows[6][IW];
    const int tid = threadIdx.x;
    const int j = blockIdx.y;
    const int y0 = blockIdx.x * 4;
    const ushort_t* src = qkvb + (long)j * NPIX;
    ushort_t* dst = (j < 384) ? (dwb + (long)j * NPIX) : (dwv + (long)(j - 384) * NPIX);
    float wv[9];
    #pragma unroll
    for (int t = 0; t < 9; t++) wv[t] = wdw[j * 9 + t];
    for (int e = tid; e < 6 * 128; e += 256) {
        int r = e >> 7, xh = e & 127;
        int yy = y0 - 1 + r;
        ushort2 val = (yy >= 0 && yy <= 255)
            ? *reinterpret_cast<const ushort2*>(src + yy * IW + xh * 2)
            : make_ushort2(0, 0);
        *reinterpret_cast<ushort2*>(&rows[r][xh * 2]) = val;
    }
    __syncthreads();
    const int x = tid;
    #pragma unroll
    for (int r = 0; r < 4; r++) {
        float a = 0.f;
        #pragma unroll
        for (int dy = 0; dy < 3; dy++) {
            const ushort_t* rw = rows[r + dy];
            if (x > 0)   a += wv[dy * 3 + 0] * b2f(rw[x - 1]);
                         a += wv[dy * 3 + 1] * b2f(rw[x]);
            if (x < 255) a += wv[dy * 3 + 2] * b2f(rw[x + 1]);
        }
        dst[(y0 + r) * IW + x] = f2b(a);
    }
}

// ---------------- K2G: MFMA Gram partials, fragments straight from global.
// grid (64 chunks, 4 heads), 4 waves; wave owns 256-px K-slice (8 MFMA K-steps).
__global__ __launch_bounds__(256) void k2_gram_mfma(const ushort_t* __restrict__ dwb,
                                                    float* __restrict__ Spt,
                                                    float* __restrict__ sqp) {
    const int tid = threadIdx.x;
    const int lane = tid & 63;
    const int wave = tid >> 6;
    const int chunk = blockIdx.x;
    const int h = blockIdx.y;
    const int r15 = lane & 15;
    const int g = lane >> 4;
    const long n0 = (long)chunk * 1024 + wave * 256;
    const ushort_t* qb = dwb + (long)(h * 48) * NPIX + n0;
    const ushort_t* kb = dwb + (long)(192 + h * 48) * NPIX + n0;

    f32x4 acc[3][3];
    #pragma unroll
    for (int mi = 0; mi < 3; mi++)
        #pragma unroll
        for (int nj = 0; nj < 3; nj++)
            acc[mi][nj] = (f32x4){0.f, 0.f, 0.f, 0.f};
    float ssq[3] = {0.f, 0.f, 0.f}, ssk[3] = {0.f, 0.f, 0.f};

    for (int ks = 0; ks < 8; ks++) {
        const int off = ks * 32 + g * 8;
        bf16x8 a[3], bfr[3];
        #pragma unroll
        for (int mi = 0; mi < 3; mi++)
            a[mi] = *reinterpret_cast<const bf16x8*>(qb + (long)(mi * 16 + r15) * NPIX + off);
        #pragma unroll
        for (int nj = 0; nj < 3; nj++)
            bfr[nj] = *reinterpret_cast<const bf16x8*>(kb + (long)(nj * 16 + r15) * NPIX + off);
        #pragma unroll
        for (int mi = 0; mi < 3; mi++)
            #pragma unroll
            for (int j = 0; j < 8; j++) {
                float f = b2f((ushort_t)a[mi][j]);
                ssq[mi] += f * f;
            }
        #pragma unroll
        for (int nj = 0; nj < 3; nj++)
            #pragma unroll
            for (int j = 0; j < 8; j++) {
                float f = b2f((ushort_t)bfr[nj][j]);
                ssk[nj] += f * f;
            }
        #pragma unroll
        for (int mi = 0; mi < 3; mi++)
            #pragma unroll
            for (int nj = 0; nj < 3; nj++)
                acc[mi][nj] = __builtin_amdgcn_mfma_f32_16x16x32_bf16(a[mi], bfr[nj], acc[mi][nj], 0, 0, 0);
    }

    const int cw = chunk * 4 + wave;
    float* outb = Spt + (long)cw * 9216 + h * 2304;
    const int gq = g * 4;
    #pragma unroll
    for (int mi = 0; mi < 3; mi++)
        #pragma unroll
        for (int nj = 0; nj < 3; nj++)
            #pragma unroll
            for (int r = 0; r < 4; r++)
                outb[(mi * 16 + gq + r) * 48 + nj * 16 + r15] = acc[mi][nj][r];

    #pragma unroll
    for (int mi = 0; mi < 3; mi++) {
        ssq[mi] += __shfl_xor(ssq[mi], 16, 64);
        ssq[mi] += __shfl_xor(ssq[mi], 32, 64);
        ssk[mi] += __shfl_xor(ssk[mi], 16, 64);
        ssk[mi] += __shfl_xor(ssk[mi], 32, 64);
    }
    if (lane < 16) {
        float* sqb = sqp + (long)cw * 384;
        #pragma unroll
        for (int mi = 0; mi < 3; mi++) {
            sqb[h * 48 + mi * 16 + lane] = ssq[mi];
            sqb[192 + h * 48 + mi * 16 + lane] = ssk[mi];
        }
    }
}

// ---------------- K3A2: coalesced two-stage reduce over cw (256 slots, 8 segs of 32)
__global__ __launch_bounds__(256) void k3a_reduce2(const float* __restrict__ Spt,
                                                   const float* __restrict__ sqp,
                                                   float* __restrict__ S1,
                                                   float* __restrict__ sq1) {
    const int seg = blockIdx.y;
    const int w = blockIdx.x * 256 + threadIdx.x;
    if (w < 9216) {
        const float* p = Spt + (long)seg * 32 * 9216 + w;
        float s = 0.f;
        for (int i = 0; i < 32; i++) s += p[(long)i * 9216];
        S1[seg * 9216 + w] = s;
    } else if (w < 9600) {
        const int c = w - 9216;
        const float* p = sqp + (long)seg * 32 * 384 + c;
        float s = 0.f;
        for (int i = 0; i < 32; i++) s += p[i * 384];
        sq1[seg * 384 + c] = s;
    }
}

// ---------------- K3b: norms, noise MLP, softmax -> attn[4][48][48]
__global__ __launch_bounds__(256) void k3b_attn(const float* __restrict__ S1,
                                                const float* __restrict__ sq1,
                                                const float* __restrict__ noise,
                                                const float* __restrict__ btemp,
                                                const float* __restrict__ w_nm1,
                                                const float* __restrict__ w_nm2,
                                                float* __restrict__ attn, int b) {
    __shared__ float sA[48][49];
    __shared__ float invq[48], invk[48];
    __shared__ float stemp;
    const int h = blockIdx.x, tid = threadIdx.x;
    for (int e = tid; e < 2304; e += 256) {
        float s = 0.f;
        #pragma unroll
        for (int seg = 0; seg < 8; seg++) s += S1[seg * 9216 + h * 2304 + e];
        sA[e / 48][e % 48] = s;
    }
    if (tid < 96) {
        int c = (tid < 48) ? (h * 48 + tid) : (192 + h * 48 + (tid - 48));
        float s = 0.f;
        #pragma unroll
        for (int seg = 0; seg < 8; seg++) s += sq1[seg * 384 + c];
        float inv = 1.f / fmaxf(sqrtf(s), 1e-12f);
        if (tid < 48) invq[tid] = inv; else invk[tid - 48] = inv;
    }
    if (tid == 0) {
        float nz = noise[b];
        float a = 0.f;
        for (int i = 0; i < 48; i++) {
            float t = w_nm1[i] * nz;
            t = (t >= 0.f) ? t : 0.2f * t;
            a += w_nm2[h * 48 + i] * t;
        }
        float sig = 1.f / (1.f + expf(-a));
        stemp = btemp[h] * (2.f - sig);
    }
    __syncthreads();
    for (int e = tid; e < 2304; e += 256) {
        int c = e / 48, d = e % 48;
        sA[c][d] *= invq[c] * invk[d] * stemp;
    }
    __syncthreads();
    if (tid < 48) {
        float m = -1e30f;
        for (int d = 0; d < 48; d++) m = fmaxf(m, sA[tid][d]);
        float sum = 0.f;
        for (int d = 0; d < 48; d++) {
            float e_ = expf(sA[tid][d] - m);
            sA[tid][d] = e_;
            sum += e_;
        }
        float r = 1.f / sum;
        for (int d = 0; d < 48; d++)
            attn[h * 2304 + tid * 48 + d] = sA[tid][d] * r;
    }
}

// ---------------- K4: W_eff[o][j] bf16 = sum_c w_out[o][h*48+c] * attn[h][c][d]
__global__ __launch_bounds__(256) void k4_weff(const float* __restrict__ w_out,
                                               const float* __restrict__ attn,
                                               ushort_t* __restrict__ weffb) {
    int e = blockIdx.x * 256 + threadIdx.x;
    int o = e / 192, j = e % 192;
    int h = j / 48, d = j % 48;
    const float* wr = w_out + o * 192 + h * 48;
    const float* ar = attn + h * 2304 + d;
    float s = 0.f;
    #pragma unroll
    for (int c = 0; c < 48; c++) s += wr[c] * ar[c * 48];
    weffb[e] = f2b(s);
}

extern "C" void kernel_launch(void* const* d_in, const int* in_sizes, int n_in,
                              void* d_out, int out_size, void* d_ws, size_t ws_size,
                              hipStream_t stream) {
    const float* x      = (const float*)d_in[0];
    const float* noise  = (const float*)d_in[1];
    const float* btemp  = (const float*)d_in[2];
    const float* w_nm1  = (const float*)d_in[3];
    const float* w_nm2  = (const float*)d_in[4];
    const float* w_qkv  = (const float*)d_in[5];
    const float* w_dw   = (const float*)d_in[6];
    const float* w_out  = (const float*)d_in[7];
    float* out = (float*)d_out;
    float* ws = (float*)d_ws;

    // Workspace (float-slot offsets), peak 38,010,880 floats = 152.0 MB:
    //  region A [0, 18874368): qkvb bf16[576][NPIX] (live kgemm1..kdw)
    //    - after kdw: Spt[256][9216], sqp[256][384], S1, sq1, attn, weffb alias it
    //  region B [18874368, 25165824): dwv bf16[192][NPIX] (kdw..kgemm2)
    //  region C [25427968, 38010880): dwb bf16[384][NPIX] (kdw..k2g)
    ushort_t* qkvb = (ushort_t*)ws;
    float* Spt  = ws;                      // 2,359,296
    float* sqp  = ws + 9437184;            // 98,304
    float* S1   = ws + 9830400;            // 73,728
    float* sq1  = ws + 9904128;            // 3,072
    float* attn = ws + 9907200;            // 9,216
    ushort_t* weffb = (ushort_t*)(ws + 9916416);
    ushort_t* dwv = (ushort_t*)(ws + 18874368);
    ushort_t* dwb = (ushort_t*)(ws + 25427968);

    for (int b = 0; b < 2; b++) {
        const float* xb = x + (long)b * 192 * NPIX;
        float* outb = out + (long)b * 192 * NPIX;
        kgemm_fused<1, 0, 1><<<512, 256, 0, stream>>>(w_qkv, xb, qkvb, 9);
        kdw_conv<<<dim3(64, 576), 256, 0, stream>>>(qkvb, w_dw, dwb, dwv);
        k2_gram_mfma<<<dim3(64, 4), 256, 0, stream>>>(dwb, Spt, sqp);
        k3a_reduce2<<<dim3(38, 8), 256, 0, stream>>>(Spt, sqp, S1, sq1);
        k3b_attn<<<4, 256, 0, stream>>>(S1, sq1, noise, btemp, w_nm1, w_nm2, attn, b);
        k4_weff<<<144, 256, 0, stream>>>(w_out, attn, weffb);
        kgemm_fused<0, 1, 0><<<512, 256, 0, stream>>>(weffb, dwv, outb, 3);
    }
}

// Round 11
// 239.548 us; speedup vs baseline: 10.5871x; 1.1592x over previous
//
#include <hip/hip_runtime.h>
#include <hip/hip_bf16.h>

#define NPIX 65536
#define IW 256

typedef unsigned short ushort_t;
typedef __attribute__((ext_vector_type(8))) short bf16x8;
typedef __attribute__((ext_vector_type(4))) float f32x4;

__device__ __forceinline__ float b2f(ushort_t u) {
    union { unsigned int i; float f; } v;
    v.i = ((unsigned int)u) << 16;
    return v.f;
}
__device__ __forceinline__ ushort_t f2b(float f) {
    __hip_bfloat16 h = __float2bfloat16(f);
    return *reinterpret_cast<ushort_t*>(&h);
}

// ---------------- KGEMM (B-stationary, fused transpose staging, MFMA bf16)
// C[m][n] = sum_k A[m][k] * B[k][n];  B source is row-major [192][NPIX]
// (fp32 if B_F32 else bf16). grid = 512 n-tiles of 128.
template<int B_F32, int A_BF16, int OUT_BF16>
__global__ __launch_bounds__(256) void kgemm_fused(const void* __restrict__ Aptr,
                                                   const void* __restrict__ Bsrc,
                                                   void* __restrict__ Cout,
                                                   int mtiles) {
    __shared__ ushort_t Bs[128 * 200];
    __shared__ ushort_t AsLu[64 * 200];   // Lu[192][66] during B-stage; As after
    const int tid = threadIdx.x;
    const int lane = tid & 63;
    const int wave = tid >> 6;
    const long n_base = (long)blockIdx.x * 128;

    // ---- B-stage with in-LDS transpose: two 64-px halves
    ushort_t (*Lu)[66] = reinterpret_cast<ushort_t (*)[66]>(AsLu);
    #pragma unroll
    for (int half = 0; half < 2; half++) {
        const long n0 = n_base + half * 64;
        __syncthreads();  // Lu reuse between halves
        #pragma unroll
        for (int i = 0; i < 24; i++) {     // 192 rows x 32 elem-pairs
            int e = tid + i * 256;
            int k = e >> 5, n2 = e & 31;
            ushort2 o;
            if (B_F32) {
                float2 v = *reinterpret_cast<const float2*>(
                    (const float*)Bsrc + (long)k * NPIX + n0 + n2 * 2);
                o = make_ushort2(f2b(v.x), f2b(v.y));
            } else {
                o = *reinterpret_cast<const ushort2*>(
                    (const ushort_t*)Bsrc + (long)k * NPIX + n0 + n2 * 2);
            }
            *reinterpret_cast<ushort2*>(&Lu[k][n2 * 2]) = o;
        }
        __syncthreads();
        const int n = tid >> 2, seg = tid & 3;
        const int kb = seg * 48;
        ushort_t* dst = &Bs[(half * 64 + n) * 200 + kb];
        #pragma unroll
        for (int w = 0; w < 6; w++) {
            unsigned int p0 = (unsigned int)Lu[kb + w * 8 + 0][n] | ((unsigned int)Lu[kb + w * 8 + 1][n] << 16);
            unsigned int p1 = (unsigned int)Lu[kb + w * 8 + 2][n] | ((unsigned int)Lu[kb + w * 8 + 3][n] << 16);
            unsigned int p2 = (unsigned int)Lu[kb + w * 8 + 4][n] | ((unsigned int)Lu[kb + w * 8 + 5][n] << 16);
            unsigned int p3 = (unsigned int)Lu[kb + w * 8 + 6][n] | ((unsigned int)Lu[kb + w * 8 + 7][n] << 16);
            *reinterpret_cast<int4*>(dst + w * 8) = make_int4(p0, p1, p2, p3);
        }
    }

    const int r15 = lane & 15;
    const int g8 = (lane >> 4) * 8;
    const int gq = (lane >> 4) * 4;
    const int nw = wave * 32;

    // ---- m-tile loop; AsLu now holds the A tile
    for (int mt = 0; mt < mtiles; mt++) {
        const int m_base = mt * 64;
        __syncthreads();
        #pragma unroll
        for (int i = 0; i < 12; i++) {     // 64 x 48 ushort4 chunks
            int c = tid + i * 256;
            int m = c / 48, k4 = c % 48;
            if (A_BF16) {
                const ushort_t* A = (const ushort_t*)Aptr;
                ushort4 v = *reinterpret_cast<const ushort4*>(A + (long)(m_base + m) * 192 + k4 * 4);
                *reinterpret_cast<ushort4*>(&AsLu[m * 200 + k4 * 4]) = v;
            } else {
                const float* A = (const float*)Aptr;
                float4 v = *reinterpret_cast<const float4*>(A + (long)(m_base + m) * 192 + k4 * 4);
                ushort4 o = make_ushort4(f2b(v.x), f2b(v.y), f2b(v.z), f2b(v.w));
                *reinterpret_cast<ushort4*>(&AsLu[m * 200 + k4 * 4]) = o;
            }
        }
        __syncthreads();

        f32x4 acc[4][2];
        #pragma unroll
        for (int mi = 0; mi < 4; mi++)
            #pragma unroll
            for (int ni = 0; ni < 2; ni++)
                acc[mi][ni] = (f32x4){0.f, 0.f, 0.f, 0.f};

        #pragma unroll
        for (int kk = 0; kk < 192; kk += 32) {
            bf16x8 a[4], b[2];
            #pragma unroll
            for (int mi = 0; mi < 4; mi++)
                a[mi] = *reinterpret_cast<const bf16x8*>(&AsLu[(mi * 16 + r15) * 200 + kk + g8]);
            #pragma unroll
            for (int ni = 0; ni < 2; ni++)
                b[ni] = *reinterpret_cast<const bf16x8*>(&Bs[(nw + ni * 16 + r15) * 200 + kk + g8]);
            #pragma unroll
            for (int mi = 0; mi < 4; mi++)
                #pragma unroll
                for (int ni = 0; ni < 2; ni++)
                    acc[mi][ni] = __builtin_amdgcn_mfma_f32_16x16x32_bf16(a[mi], b[ni], acc[mi][ni], 0, 0, 0);
        }

        #pragma unroll
        for (int mi = 0; mi < 4; mi++)
            #pragma unroll
            for (int ni = 0; ni < 2; ni++)
                #pragma unroll
                for (int r = 0; r < 4; r++) {
                    long m = m_base + mi * 16 + gq + r;
                    long n = n_base + nw + ni * 16 + r15;
                    if (OUT_BF16) ((ushort_t*)Cout)[m * NPIX + n] = f2b(acc[mi][ni][r]);
                    else          ((float*)Cout)[m * NPIX + n] = acc[mi][ni][r];
                }
    }
}

// ---------------- KDW: register-sliding-window depthwise 3x3, 16 rows/block.
// grid (16, 576); thread (ty,tx16) computes 16 contiguous px of one row.
__global__ __launch_bounds__(256) void kdw_conv(const ushort_t* __restrict__ qkvb,
                                                const float* __restrict__ wdw,
                                                ushort_t* __restrict__ dwb,
                                                ushort_t* __restrict__ dwv) {
    __shared__ ushort_t rows[18][IW];
    const int tid = threadIdx.x;
    const int j = blockIdx.y;
    const int y0 = blockIdx.x * 16;
    const ushort_t* src = qkvb + (long)j * NPIX;
    ushort_t* dst = (j < 384) ? (dwb + (long)j * NPIX) : (dwv + (long)(j - 384) * NPIX);
    float wv[9];
    #pragma unroll
    for (int t = 0; t < 9; t++) wv[t] = wdw[j * 9 + t];

    // stage 18 rows (halo y0-1 .. y0+16) as ushort4
    for (int e = tid; e < 18 * 64; e += 256) {
        int r = e >> 6, x4 = e & 63;
        int yy = y0 - 1 + r;
        ushort4 val = (yy >= 0 && yy <= 255)
            ? *reinterpret_cast<const ushort4*>(src + yy * IW + x4 * 4)
            : make_ushort4(0, 0, 0, 0);
        *reinterpret_cast<ushort4*>(&rows[r][x4 * 4]) = val;
    }
    __syncthreads();

    const int ty = tid >> 4;
    const int tx = (tid & 15) * 16;
    float win[3][18];
    #pragma unroll
    for (int dy = 0; dy < 3; dy++) {
        const ushort_t* rw = rows[ty + dy];
        win[dy][0] = (tx > 0) ? b2f(rw[tx - 1]) : 0.f;
        #pragma unroll
        for (int i = 0; i < 16; i++) win[dy][i + 1] = b2f(rw[tx + i]);
        win[dy][17] = (tx < 240) ? b2f(rw[tx + 16]) : 0.f;
    }

    unsigned int packed[8];
    #pragma unroll
    for (int p2 = 0; p2 < 8; p2++) {
        unsigned int pk = 0;
        #pragma unroll
        for (int half = 0; half < 2; half++) {
            const int p = p2 * 2 + half;
            float a = 0.f;
            #pragma unroll
            for (int dy = 0; dy < 3; dy++)
                #pragma unroll
                for (int dx = 0; dx < 3; dx++)
                    a += wv[dy * 3 + dx] * win[dy][p + dx];
            pk |= ((unsigned int)f2b(a)) << (16 * half);
        }
        packed[p2] = pk;
    }
    int4* dp = reinterpret_cast<int4*>(dst + (y0 + ty) * IW + tx);
    dp[0] = make_int4(packed[0], packed[1], packed[2], packed[3]);
    dp[1] = make_int4(packed[4], packed[5], packed[6], packed[7]);
}

// ---------------- K2G: MFMA Gram partials, fragments straight from global.
// grid (64 chunks, 4 heads), 4 waves; wave owns 256-px K-slice (8 MFMA K-steps).
__global__ __launch_bounds__(256) void k2_gram_mfma(const ushort_t* __restrict__ dwb,
                                                    float* __restrict__ Spt,
                                                    float* __restrict__ sqp) {
    const int tid = threadIdx.x;
    const int lane = tid & 63;
    const int wave = tid >> 6;
    const int chunk = blockIdx.x;
    const int h = blockIdx.y;
    const int r15 = lane & 15;
    const int g = lane >> 4;
    const long n0 = (long)chunk * 1024 + wave * 256;
    const ushort_t* qb = dwb + (long)(h * 48) * NPIX + n0;
    const ushort_t* kb = dwb + (long)(192 + h * 48) * NPIX + n0;

    f32x4 acc[3][3];
    #pragma unroll
    for (int mi = 0; mi < 3; mi++)
        #pragma unroll
        for (int nj = 0; nj < 3; nj++)
            acc[mi][nj] = (f32x4){0.f, 0.f, 0.f, 0.f};
    float ssq[3] = {0.f, 0.f, 0.f}, ssk[3] = {0.f, 0.f, 0.f};

    for (int ks = 0; ks < 8; ks++) {
        const int off = ks * 32 + g * 8;
        bf16x8 a[3], bfr[3];
        #pragma unroll
        for (int mi = 0; mi < 3; mi++)
            a[mi] = *reinterpret_cast<const bf16x8*>(qb + (long)(mi * 16 + r15) * NPIX + off);
        #pragma unroll
        for (int nj = 0; nj < 3; nj++)
            bfr[nj] = *reinterpret_cast<const bf16x8*>(kb + (long)(nj * 16 + r15) * NPIX + off);
        #pragma unroll
        for (int mi = 0; mi < 3; mi++)
            #pragma unroll
            for (int j = 0; j < 8; j++) {
                float f = b2f((ushort_t)a[mi][j]);
                ssq[mi] += f * f;
            }
        #pragma unroll
        for (int nj = 0; nj < 3; nj++)
            #pragma unroll
            for (int j = 0; j < 8; j++) {
                float f = b2f((ushort_t)bfr[nj][j]);
                ssk[nj] += f * f;
            }
        #pragma unroll
        for (int mi = 0; mi < 3; mi++)
            #pragma unroll
            for (int nj = 0; nj < 3; nj++)
                acc[mi][nj] = __builtin_amdgcn_mfma_f32_16x16x32_bf16(a[mi], bfr[nj], acc[mi][nj], 0, 0, 0);
    }

    const int cw = chunk * 4 + wave;
    float* outb = Spt + (long)cw * 9216 + h * 2304;
    const int gq = g * 4;
    #pragma unroll
    for (int mi = 0; mi < 3; mi++)
        #pragma unroll
        for (int nj = 0; nj < 3; nj++)
            #pragma unroll
            for (int r = 0; r < 4; r++)
                outb[(mi * 16 + gq + r) * 48 + nj * 16 + r15] = acc[mi][nj][r];

    #pragma unroll
    for (int mi = 0; mi < 3; mi++) {
        ssq[mi] += __shfl_xor(ssq[mi], 16, 64);
        ssq[mi] += __shfl_xor(ssq[mi], 32, 64);
        ssk[mi] += __shfl_xor(ssk[mi], 16, 64);
        ssk[mi] += __shfl_xor(ssk[mi], 32, 64);
    }
    if (lane < 16) {
        float* sqb = sqp + (long)cw * 384;
        #pragma unroll
        for (int mi = 0; mi < 3; mi++) {
            sqb[h * 48 + mi * 16 + lane] = ssq[mi];
            sqb[192 + h * 48 + mi * 16 + lane] = ssk[mi];
        }
    }
}

// ---------------- K3A2: coalesced two-stage reduce over cw (256 slots, 8 segs of 32)
__global__ __launch_bounds__(256) void k3a_reduce2(const float* __restrict__ Spt,
                                                   const float* __restrict__ sqp,
                                                   float* __restrict__ S1,
                                                   float* __restrict__ sq1) {
    const int seg = blockIdx.y;
    const int w = blockIdx.x * 256 + threadIdx.x;
    if (w < 9216) {
        const float* p = Spt + (long)seg * 32 * 9216 + w;
        float s = 0.f;
        for (int i = 0; i < 32; i++) s += p[(long)i * 9216];
        S1[seg * 9216 + w] = s;
    } else if (w < 9600) {
        const int c = w - 9216;
        const float* p = sqp + (long)seg * 32 * 384 + c;
        float s = 0.f;
        for (int i = 0; i < 32; i++) s += p[i * 384];
        sq1[seg * 384 + c] = s;
    }
}

// ---------------- K3b: norms, noise MLP, softmax -> attn[4][48][48]
__global__ __launch_bounds__(256) void k3b_attn(const float* __restrict__ S1,
                                                const float* __restrict__ sq1,
                                                const float* __restrict__ noise,
                                                const float* __restrict__ btemp,
                                                const float* __restrict__ w_nm1,
                                                const float* __restrict__ w_nm2,
                                                float* __restrict__ attn, int b) {
    __shared__ float sA[48][49];
    __shared__ float invq[48], invk[48];
    __shared__ float stemp;
    const int h = blockIdx.x, tid = threadIdx.x;
    for (int e = tid; e < 2304; e += 256) {
        float s = 0.f;
        #pragma unroll
        for (int seg = 0; seg < 8; seg++) s += S1[seg * 9216 + h * 2304 + e];
        sA[e / 48][e % 48] = s;
    }
    if (tid < 96) {
        int c = (tid < 48) ? (h * 48 + tid) : (192 + h * 48 + (tid - 48));
        float s = 0.f;
        #pragma unroll
        for (int seg = 0; seg < 8; seg++) s += sq1[seg * 384 + c];
        float inv = 1.f / fmaxf(sqrtf(s), 1e-12f);
        if (tid < 48) invq[tid] = inv; else invk[tid - 48] = inv;
    }
    if (tid == 0) {
        float nz = noise[b];
        float a = 0.f;
        for (int i = 0; i < 48; i++) {
            float t = w_nm1[i] * nz;
            t = (t >= 0.f) ? t : 0.2f * t;
            a += w_nm2[h * 48 + i] * t;
        }
        float sig = 1.f / (1.f + expf(-a));
        stemp = btemp[h] * (2.f - sig);
    }
    __syncthreads();
    for (int e = tid; e < 2304; e += 256) {
        int c = e / 48, d = e % 48;
        sA[c][d] *= invq[c] * invk[d] * stemp;
    }
    __syncthreads();
    if (tid < 48) {
        float m = -1e30f;
        for (int d = 0; d < 48; d++) m = fmaxf(m, sA[tid][d]);
        float sum = 0.f;
        for (int d = 0; d < 48; d++) {
            float e_ = expf(sA[tid][d] - m);
            sA[tid][d] = e_;
            sum += e_;
        }
        float r = 1.f / sum;
        for (int d = 0; d < 48; d++)
            attn[h * 2304 + tid * 48 + d] = sA[tid][d] * r;
    }
}

// ---------------- K4: W_eff[o][j] bf16 = sum_c w_out[o][h*48+c] * attn[h][c][d]
__global__ __launch_bounds__(256) void k4_weff(const float* __restrict__ w_out,
                                               const float* __restrict__ attn,
                                               ushort_t* __restrict__ weffb) {
    int e = blockIdx.x * 256 + threadIdx.x;
    int o = e / 192, j = e % 192;
    int h = j / 48, d = j % 48;
    const float* wr = w_out + o * 192 + h * 48;
    const float* ar = attn + h * 2304 + d;
    float s = 0.f;
    #pragma unroll
    for (int c = 0; c < 48; c++) s += wr[c] * ar[c * 48];
    weffb[e] = f2b(s);
}

extern "C" void kernel_launch(void* const* d_in, const int* in_sizes, int n_in,
                              void* d_out, int out_size, void* d_ws, size_t ws_size,
                              hipStream_t stream) {
    const float* x      = (const float*)d_in[0];
    const float* noise  = (const float*)d_in[1];
    const float* btemp  = (const float*)d_in[2];
    const float* w_nm1  = (const float*)d_in[3];
    const float* w_nm2  = (const float*)d_in[4];
    const float* w_qkv  = (const float*)d_in[5];
    const float* w_dw   = (const float*)d_in[6];
    const float* w_out  = (const float*)d_in[7];
    float* out = (float*)d_out;
    float* ws = (float*)d_ws;

    // Workspace (float-slot offsets), peak 38,010,880 floats = 152.0 MB:
    //  region A [0, 18874368): qkvb bf16[576][NPIX] (live kgemm1..kdw)
    //    - after kdw: Spt[256][9216], sqp[256][384], S1, sq1, attn, weffb alias it
    //  region B [18874368, 25165824): dwv bf16[192][NPIX] (kdw..kgemm2)
    //  region C [25427968, 38010880): dwb bf16[384][NPIX] (kdw..k2g)
    ushort_t* qkvb = (ushort_t*)ws;
    float* Spt  = ws;                      // 2,359,296
    float* sqp  = ws + 9437184;            // 98,304
    float* S1   = ws + 9830400;            // 73,728
    float* sq1  = ws + 9904128;            // 3,072
    float* attn = ws + 9907200;            // 9,216
    ushort_t* weffb = (ushort_t*)(ws + 9916416);
    ushort_t* dwv = (ushort_t*)(ws + 18874368);
    ushort_t* dwb = (ushort_t*)(ws + 25427968);

    for (int b = 0; b < 2; b++) {
        const float* xb = x + (long)b * 192 * NPIX;
        float* outb = out + (long)b * 192 * NPIX;
        kgemm_fused<1, 0, 1><<<512, 256, 0, stream>>>(w_qkv, xb, qkvb, 9);
        kdw_conv<<<dim3(16, 576), 256, 0, stream>>>(qkvb, w_dw, dwb, dwv);
        k2_gram_mfma<<<dim3(64, 4), 256, 0, stream>>>(dwb, Spt, sqp);
        k3a_reduce2<<<dim3(38, 8), 256, 0, stream>>>(Spt, sqp, S1, sq1);
        k3b_attn<<<4, 256, 0, stream>>>(S1, sq1, noise, btemp, w_nm1, w_nm2, attn, b);
        k4_weff<<<144, 256, 0, stream>>>(w_out, attn, weffb);
        kgemm_fused<0, 1, 0><<<512, 256, 0, stream>>>(weffb, dwv, outb, 3);
    }
}